// Round 1
// baseline (1519.660 us; speedup 1.0000x reference)
//
#include <hip/hip_runtime.h>
#include <math.h>

#define N_NODES 50000
#define N_EDGES 800000
#define CDIM    128
#define GDIM    128
#define L0DIM   512
#define L1DIM   256

// ============================ CSR build =================================
__global__ void hist_kernel(const int* __restrict__ dst, int* counts, int E) {
  int e = blockIdx.x * 256 + threadIdx.x;
  if (e < E) atomicAdd(&counts[dst[e]], 1);
}

__global__ void scan_kernel(const int* __restrict__ counts, int* indptr, int N) {
  __shared__ int s[1024];
  __shared__ int carry;
  int tid = threadIdx.x;
  if (tid == 0) carry = 0;
  __syncthreads();
  for (int base = 0; base < N; base += 1024) {
    int i = base + tid;
    int v = (i < N) ? counts[i] : 0;
    s[tid] = v;
    __syncthreads();
    for (int off = 1; off < 1024; off <<= 1) {
      int t = (tid >= off) ? s[tid - off] : 0;
      __syncthreads();
      s[tid] += t;
      __syncthreads();
    }
    if (i < N) indptr[i] = carry + s[tid] - v;  // exclusive scan
    int tot = s[1023];
    __syncthreads();
    if (tid == 0) carry += tot;
    __syncthreads();
  }
  if (tid == 0) indptr[N] = carry;
}

__global__ void scatter_kernel(const int* __restrict__ dst, const int* __restrict__ indptr,
                               int* cursor, int* eidx, int E) {
  int e = blockIdx.x * 256 + threadIdx.x;
  if (e < E) {
    int d = dst[e];
    int pos = atomicAdd(&cursor[d], 1);
    eidx[indptr[d] + pos] = e;
  }
}

// ===================== layer 0 (din=4) q/k/v/skip ========================
__global__ void l0_qkvs(const float* __restrict__ x,
                        const float* __restrict__ Wq, const float* __restrict__ bq,
                        const float* __restrict__ Wk, const float* __restrict__ bk,
                        const float* __restrict__ Wv, const float* __restrict__ bv,
                        const float* __restrict__ Ws, const float* __restrict__ bs,
                        float* __restrict__ q, float* __restrict__ k,
                        float* __restrict__ v, float* __restrict__ hs, int N) {
  __shared__ float W[4][4][128];  // [mat][j][c]
  __shared__ float B[4][128];
  int tid = threadIdx.x;
  for (int i = tid; i < 4 * 128; i += 256) {
    W[0][i >> 7][i & 127] = Wq[i];
    W[1][i >> 7][i & 127] = Wk[i];
    W[2][i >> 7][i & 127] = Wv[i];
    W[3][i >> 7][i & 127] = Ws[i];
  }
  for (int i = tid; i < 128; i += 256) {
    B[0][i] = bq[i]; B[1][i] = bk[i]; B[2][i] = bv[i]; B[3][i] = bs[i];
  }
  __syncthreads();
  int gid = blockIdx.x * 256 + tid;
  int n = gid >> 7, c = gid & 127;
  if (n >= N) return;
  float x0 = x[n * 4 + 0], x1 = x[n * 4 + 1], x2 = x[n * 4 + 2], x3 = x[n * 4 + 3];
  q[n * 128 + c]  = x0 * W[0][0][c] + x1 * W[0][1][c] + x2 * W[0][2][c] + x3 * W[0][3][c] + B[0][c];
  k[n * 128 + c]  = x0 * W[1][0][c] + x1 * W[1][1][c] + x2 * W[1][2][c] + x3 * W[1][3][c] + B[1][c];
  v[n * 128 + c]  = x0 * W[2][0][c] + x1 * W[2][1][c] + x2 * W[2][2][c] + x3 * W[2][3][c] + B[2][c];
  hs[n * 128 + c] = x0 * W[3][0][c] + x1 * W[3][1][c] + x2 * W[3][2][c] + x3 * W[3][3][c] + B[3][c];
}

// ================= layers 1-2 GEMM: [N,128] @ [128,128] ==================
// blockIdx.z selects which of {Wq,Wk,Wv,Ws}; 64 rows x 128 cols per block.
__global__ __launch_bounds__(256) void gemm_qkvs(
    const float* __restrict__ H,
    const float* __restrict__ Wq, const float* __restrict__ bq,
    const float* __restrict__ Wk, const float* __restrict__ bk,
    const float* __restrict__ Wv, const float* __restrict__ bv,
    const float* __restrict__ Ws, const float* __restrict__ bs,
    float* __restrict__ q, float* __restrict__ k, float* __restrict__ v,
    float* __restrict__ hs, int N) {
  int z = blockIdx.z;
  const float* W  = (z == 0) ? Wq : (z == 1) ? Wk : (z == 2) ? Wv : Ws;
  const float* bb = (z == 0) ? bq : (z == 1) ? bk : (z == 2) ? bv : bs;
  float* O        = (z == 0) ? q  : (z == 1) ? k  : (z == 2) ? v  : hs;

  __shared__ float hT[16][64];   // [k][row]
  __shared__ float Wl[16][128];  // [k][col]
  int tid = threadIdx.x;
  int tx = tid & 31;   // col group: cols 4*tx .. 4*tx+3
  int ty = tid >> 5;   // row group: rows 8*ty .. 8*ty+7
  int n0 = blockIdx.x * 64;

  float acc[8][4];
#pragma unroll
  for (int r = 0; r < 8; r++)
#pragma unroll
    for (int c = 0; c < 4; c++) acc[r][c] = 0.f;

  int lrow = tid >> 2;          // 0..63
  int lkk  = (tid & 3) * 4;     // 0,4,8,12
  int grow = min(n0 + lrow, N - 1);
  int wrow = tid >> 4;          // 0..15
  int wc   = (tid & 15) * 8;    // 0..120

  for (int k0 = 0; k0 < 128; k0 += 16) {
    float4 hv  = *(const float4*)&H[grow * 128 + k0 + lkk];
    float4 wv0 = *(const float4*)&W[(k0 + wrow) * 128 + wc];
    float4 wv1 = *(const float4*)&W[(k0 + wrow) * 128 + wc + 4];
    hT[lkk + 0][lrow] = hv.x; hT[lkk + 1][lrow] = hv.y;
    hT[lkk + 2][lrow] = hv.z; hT[lkk + 3][lrow] = hv.w;
    *(float4*)&Wl[wrow][wc]     = wv0;
    *(float4*)&Wl[wrow][wc + 4] = wv1;
    __syncthreads();
#pragma unroll
    for (int kk = 0; kk < 16; kk++) {
      float4 a0 = *(const float4*)&hT[kk][ty * 8];
      float4 a1 = *(const float4*)&hT[kk][ty * 8 + 4];
      float4 wv = *(const float4*)&Wl[kk][tx * 4];
      float ar[8] = {a0.x, a0.y, a0.z, a0.w, a1.x, a1.y, a1.z, a1.w};
      float wr[4] = {wv.x, wv.y, wv.z, wv.w};
#pragma unroll
      for (int r = 0; r < 8; r++)
#pragma unroll
        for (int c = 0; c < 4; c++) acc[r][c] = fmaf(ar[r], wr[c], acc[r][c]);
    }
    __syncthreads();
  }
  float4 bv4 = *(const float4*)&bb[tx * 4];
#pragma unroll
  for (int r = 0; r < 8; r++) {
    int n = n0 + ty * 8 + r;
    if (n < N) {
      float4 o;
      o.x = acc[r][0] + bv4.x; o.y = acc[r][1] + bv4.y;
      o.z = acc[r][2] + bv4.z; o.w = acc[r][3] + bv4.w;
      *(float4*)&O[n * 128 + tx * 4] = o;
    }
  }
}

// =========================== edge logits ================================
// one wave per 8 edges; 2 channels/lane; edge-emb computed on the fly
#define EPW 8
__global__ void edge_logits(const float* __restrict__ q, const float* __restrict__ kb,
                            const int* __restrict__ src, const int* __restrict__ dst,
                            const float* __restrict__ attr, const float* __restrict__ We,
                            float* __restrict__ logits, int E) {
  __shared__ float WeS[384];
  int tid = threadIdx.x;
  for (int i = tid; i < 384; i += 256) WeS[i] = We[i];
  __syncthreads();
  int lane = tid & 63;
  int wave = blockIdx.x * 4 + (tid >> 6);
  float w0 = WeS[2 * lane],       w1 = WeS[2 * lane + 1];
  float w2 = WeS[128 + 2 * lane], w3 = WeS[128 + 2 * lane + 1];
  float w4 = WeS[256 + 2 * lane], w5 = WeS[256 + 2 * lane + 1];
  int e0i = wave * EPW;
  int e1i = min(e0i + EPW, E);
  for (int e = e0i; e < e1i; e++) {
    int sj = src[e], dj = dst[e];
    float a0 = attr[e * 3 + 0], a1 = attr[e * 3 + 1], a2 = attr[e * 3 + 2];
    float2 qv = *(const float2*)&q[dj * 128 + 2 * lane];
    float2 kv = *(const float2*)&kb[sj * 128 + 2 * lane];
    float ee0 = a0 * w0 + a1 * w2 + a2 * w4;
    float ee1 = a0 * w1 + a1 * w3 + a2 * w5;
    float p = qv.x * (kv.x + ee0) + qv.y * (kv.y + ee1);
#pragma unroll
    for (int off = 32; off > 0; off >>= 1) p += __shfl_down(p, off);
    if (lane == 0) logits[e] = p * 0.08838834764831845f;  // 1/sqrt(128)
  }
}

// ================= node softmax + aggregate + skip + leaky ===============
// one wave per node; channels lane and lane+64; CSR in-edges
__global__ void node_attn(const float* __restrict__ v, const float* __restrict__ logits,
                          const int* __restrict__ indptr, const int* __restrict__ eidx,
                          const int* __restrict__ src, const float* __restrict__ attr,
                          const float* __restrict__ We,
                          float* __restrict__ h, int N) {
  __shared__ float WeS[384];
  int tid = threadIdx.x;
  for (int i = tid; i < 384; i += 256) WeS[i] = We[i];
  __syncthreads();
  int lane = tid & 63;
  int n = blockIdx.x * 4 + (tid >> 6);
  if (n >= N) return;
  int beg = indptr[n], end = indptr[n + 1];
  float s0 = h[n * 128 + lane], s1 = h[n * 128 + 64 + lane];
  if (end > beg) {
    float m = -3.4e38f;
    for (int i = beg + lane; i < end; i += 64) m = fmaxf(m, logits[eidx[i]]);
#pragma unroll
    for (int off = 1; off < 64; off <<= 1) m = fmaxf(m, __shfl_xor(m, off));
    float w0 = WeS[lane],      w1 = WeS[128 + lane],      w2 = WeS[256 + lane];
    float w3 = WeS[64 + lane], w4 = WeS[192 + lane],      w5 = WeS[320 + lane];
    float acc0 = 0.f, acc1 = 0.f, den = 0.f;
    for (int i = beg; i < end; i++) {
      int e = eidx[i];
      float a = __expf(logits[e] - m);
      int sj = src[e];
      float a0 = attr[e * 3 + 0], a1 = attr[e * 3 + 1], a2 = attr[e * 3 + 2];
      float ee0 = a0 * w0 + a1 * w1 + a2 * w2;
      float ee1 = a0 * w3 + a1 * w4 + a2 * w5;
      acc0 += a * (v[sj * 128 + lane] + ee0);
      acc1 += a * (v[sj * 128 + 64 + lane] + ee1);
      den += a;
    }
    float inv = 1.f / den;
    s0 += acc0 * inv;
    s1 += acc1 * inv;
  }
  s0 = (s0 > 0.f) ? s0 : 0.01f * s0;
  s1 = (s1 > 0.f) ? s1 : 0.01f * s1;
  h[n * 128 + lane] = s0;
  h[n * 128 + 64 + lane] = s1;
}

// ======================= pool (batch is sorted) ==========================
__global__ void pool_kernel(const float* __restrict__ h, const int* __restrict__ batch,
                            float* __restrict__ gout, int N) {
  int c = threadIdx.x;  // 128
  int n0 = blockIdx.x * 128;
  if (n0 >= N) return;
  int n1 = min(n0 + 128, N);
  float acc = 0.f;
  int cur = batch[n0];
  for (int n = n0; n < n1; n++) {
    int b = batch[n];
    if (b != cur) { atomicAdd(&gout[cur * 128 + c], acc); acc = 0.f; cur = b; }
    acc += h[n * 128 + c];
  }
  atomicAdd(&gout[cur * 128 + c], acc);
}

// ============================== MLP head ================================
__global__ void mlp_kernel(const float* __restrict__ in, const float* __restrict__ W,
                           const float* __restrict__ b, float* __restrict__ out,
                           int K, int M, int do_relu) {
  int g = blockIdx.x;
  for (int c = threadIdx.x; c < M; c += blockDim.x) {
    float acc = b[c];
    for (int kk = 0; kk < K; kk++) acc = fmaf(in[g * K + kk], W[kk * M + c], acc);
    out[g * M + c] = do_relu ? fmaxf(acc, 0.f) : acc;
  }
}

__global__ void mlp_final(const float* __restrict__ in, const float* __restrict__ W,
                          const float* __restrict__ b, float* __restrict__ out) {
  int tid = threadIdx.x;  // 256 = G*2
  int g = tid >> 1, p = tid & 1;
  float acc = b[p];
  for (int kk = 0; kk < L1DIM; kk++) acc = fmaf(in[g * L1DIM + kk], W[kk * 2 + p], acc);
  out[tid] = acc;
}

// ============================== launch ==================================
extern "C" void kernel_launch(void* const* d_in, const int* in_sizes, int n_in,
                              void* d_out, int out_size, void* d_ws, size_t ws_size,
                              hipStream_t stream) {
  const int N = N_NODES, E = N_EDGES;
  const float* x    = (const float*)d_in[0];
  const int*   ei   = (const int*)d_in[1];
  const float* attr = (const float*)d_in[2];
  const int*   batch= (const int*)d_in[3];
  const int* src = ei;
  const int* dst = ei + E;

  const float *Wq0 = (const float*)d_in[4],  *bq0 = (const float*)d_in[5];
  const float *Wk0 = (const float*)d_in[6],  *bk0 = (const float*)d_in[7];
  const float *Wv0 = (const float*)d_in[8],  *bv0 = (const float*)d_in[9];
  const float *We0 = (const float*)d_in[10];
  const float *Ws0 = (const float*)d_in[11], *bs0 = (const float*)d_in[12];
  const float *Wq1 = (const float*)d_in[13], *bq1 = (const float*)d_in[14];
  const float *Wk1 = (const float*)d_in[15], *bk1 = (const float*)d_in[16];
  const float *Wv1 = (const float*)d_in[17], *bv1 = (const float*)d_in[18];
  const float *We1 = (const float*)d_in[19];
  const float *Ws1 = (const float*)d_in[20], *bs1 = (const float*)d_in[21];
  const float *Wl0 = (const float*)d_in[22], *bl0 = (const float*)d_in[23];
  const float *Wl1 = (const float*)d_in[24], *bl1 = (const float*)d_in[25];
  const float *Wl2 = (const float*)d_in[26], *bl2 = (const float*)d_in[27];

  // --- workspace carve (needs ~136 MB) ---
  size_t off = 0;
  auto carve = [&](size_t bytes) {
    void* p = (char*)d_ws + off;
    off += (bytes + 255) & ~(size_t)255;
    return p;
  };
  float* hA     = (float*)carve((size_t)N * CDIM * 4);
  float* hB     = (float*)carve((size_t)N * CDIM * 4);
  float* qb     = (float*)carve((size_t)N * CDIM * 4);
  float* kb     = (float*)carve((size_t)N * CDIM * 4);
  float* vb     = (float*)carve((size_t)N * CDIM * 4);
  float* logits = (float*)carve((size_t)E * 4);
  int*   indptr = (int*)carve((size_t)(N + 1) * 4);
  int*   eidx   = (int*)carve((size_t)E * 4);
  int*   counts = (int*)carve((size_t)N * 4);
  int*   cursor = (int*)carve((size_t)N * 4);
  float* gp     = (float*)carve((size_t)GDIM * CDIM * 4);
  float* m1     = (float*)carve((size_t)GDIM * L0DIM * 4);
  float* m2     = (float*)carve((size_t)GDIM * L1DIM * 4);

  hipMemsetAsync(counts, 0, (size_t)N * 4, stream);
  hipMemsetAsync(cursor, 0, (size_t)N * 4, stream);
  hipMemsetAsync(gp, 0, (size_t)GDIM * CDIM * 4, stream);

  // CSR build (dst-grouped), reused by all 3 layers
  hist_kernel<<<(E + 255) / 256, 256, 0, stream>>>(dst, counts, E);
  scan_kernel<<<1, 1024, 0, stream>>>(counts, indptr, N);
  scatter_kernel<<<(E + 255) / 256, 256, 0, stream>>>(dst, indptr, cursor, eidx, E);

  int elBlocks = (E / EPW + 3) / 4;   // waves of 8 edges, 4 waves/block
  int naBlocks = (N + 3) / 4;

  // ---- layer 0 (din=4) ----
  l0_qkvs<<<(N * 128 + 255) / 256, 256, 0, stream>>>(
      x, Wq0, bq0, Wk0, bk0, Wv0, bv0, Ws0, bs0, qb, kb, vb, hA, N);
  edge_logits<<<elBlocks, 256, 0, stream>>>(qb, kb, src, dst, attr, We0, logits, E);
  node_attn<<<naBlocks, 256, 0, stream>>>(vb, logits, indptr, eidx, src, attr, We0, hA, N);

  // ---- layer 1 (shared weights) ----
  gemm_qkvs<<<dim3((N + 63) / 64, 1, 4), 256, 0, stream>>>(
      hA, Wq1, bq1, Wk1, bk1, Wv1, bv1, Ws1, bs1, qb, kb, vb, hB, N);
  edge_logits<<<elBlocks, 256, 0, stream>>>(qb, kb, src, dst, attr, We1, logits, E);
  node_attn<<<naBlocks, 256, 0, stream>>>(vb, logits, indptr, eidx, src, attr, We1, hB, N);

  // ---- layer 2 (same weights again) ----
  gemm_qkvs<<<dim3((N + 63) / 64, 1, 4), 256, 0, stream>>>(
      hB, Wq1, bq1, Wk1, bk1, Wv1, bv1, Ws1, bs1, qb, kb, vb, hA, N);
  edge_logits<<<elBlocks, 256, 0, stream>>>(qb, kb, src, dst, attr, We1, logits, E);
  node_attn<<<naBlocks, 256, 0, stream>>>(vb, logits, indptr, eidx, src, attr, We1, hA, N);

  // ---- pool + MLP ----
  pool_kernel<<<(N + 127) / 128, 128, 0, stream>>>(hA, batch, gp, N);
  mlp_kernel<<<GDIM, 256, 0, stream>>>(gp, Wl0, bl0, m1, CDIM, L0DIM, 1);
  mlp_kernel<<<GDIM, 256, 0, stream>>>(m1, Wl1, bl1, m2, L0DIM, L1DIM, 1);
  mlp_final<<<1, 256, 0, stream>>>(m2, Wl2, bl2, (float*)d_out);
}

// Round 2
// 1276.959 us; speedup vs baseline: 1.1901x; 1.1901x over previous
//
#include <hip/hip_runtime.h>
#include <math.h>

#define N_NODES 50000
#define N_EDGES 800000
#define CDIM    128
#define GDIM    128
#define L0DIM   512
#define L1DIM   256

// ============================ CSR build =================================
__global__ void hist_kernel(const int* __restrict__ dst, int* counts, int E) {
  int e = blockIdx.x * 256 + threadIdx.x;
  if (e < E) atomicAdd(&counts[dst[e]], 1);
}

// multi-block scan: per-block exclusive scan + block sums
__global__ void scan_blocks(const int* __restrict__ counts, int* excl, int* bsums, int N) {
  __shared__ int s[1024];
  int tid = threadIdx.x;
  int i = blockIdx.x * 1024 + tid;
  int v = (i < N) ? counts[i] : 0;
  s[tid] = v;
  __syncthreads();
  for (int off = 1; off < 1024; off <<= 1) {
    int t = (tid >= off) ? s[tid - off] : 0;
    __syncthreads();
    s[tid] += t;
    __syncthreads();
  }
  if (i < N) excl[i] = s[tid] - v;
  if (tid == 1023) bsums[blockIdx.x] = s[1023];
}

__global__ void scan_sums(int* bsums, int nb) {
  // tiny serial exclusive scan (nb ~ 49)
  if (threadIdx.x == 0) {
    int run = 0;
    for (int b = 0; b < nb; b++) { int t = bsums[b]; bsums[b] = run; run += t; }
  }
}

__global__ void scan_add(const int* __restrict__ excl, const int* __restrict__ bsums,
                         int* indptr, int N, int E) {
  int i = blockIdx.x * 1024 + threadIdx.x;
  if (i < N) indptr[i] = excl[i] + bsums[blockIdx.x];
  if (i == 0) indptr[N] = E;
}

__global__ void scatter_kernel(const int* __restrict__ dst, const int* __restrict__ indptr,
                               int* cursor, int* eidx, int E) {
  int e = blockIdx.x * 256 + threadIdx.x;
  if (e < E) {
    int d = dst[e];
    int pos = atomicAdd(&cursor[d], 1);
    eidx[indptr[d] + pos] = e;
  }
}

// ===================== layer 0 (din=4) q/k/v/skip ========================
__global__ void l0_qkvs(const float* __restrict__ x,
                        const float* __restrict__ Wq, const float* __restrict__ bq,
                        const float* __restrict__ Wk, const float* __restrict__ bk,
                        const float* __restrict__ Wv, const float* __restrict__ bv,
                        const float* __restrict__ Ws, const float* __restrict__ bs,
                        float* __restrict__ q, float* __restrict__ k,
                        float* __restrict__ v, float* __restrict__ hs, int N) {
  __shared__ float W[4][4][128];  // [mat][j][c]
  __shared__ float B[4][128];
  int tid = threadIdx.x;
  for (int i = tid; i < 4 * 128; i += 256) {
    W[0][i >> 7][i & 127] = Wq[i];
    W[1][i >> 7][i & 127] = Wk[i];
    W[2][i >> 7][i & 127] = Wv[i];
    W[3][i >> 7][i & 127] = Ws[i];
  }
  for (int i = tid; i < 128; i += 256) {
    B[0][i] = bq[i]; B[1][i] = bk[i]; B[2][i] = bv[i]; B[3][i] = bs[i];
  }
  __syncthreads();
  int gid = blockIdx.x * 256 + tid;
  int n = gid >> 7, c = gid & 127;
  if (n >= N) return;
  float x0 = x[n * 4 + 0], x1 = x[n * 4 + 1], x2 = x[n * 4 + 2], x3 = x[n * 4 + 3];
  q[n * 128 + c]  = x0 * W[0][0][c] + x1 * W[0][1][c] + x2 * W[0][2][c] + x3 * W[0][3][c] + B[0][c];
  k[n * 128 + c]  = x0 * W[1][0][c] + x1 * W[1][1][c] + x2 * W[1][2][c] + x3 * W[1][3][c] + B[1][c];
  v[n * 128 + c]  = x0 * W[2][0][c] + x1 * W[2][1][c] + x2 * W[2][2][c] + x3 * W[2][3][c] + B[2][c];
  hs[n * 128 + c] = x0 * W[3][0][c] + x1 * W[3][1][c] + x2 * W[3][2][c] + x3 * W[3][3][c] + B[3][c];
}

// ================= layers 1-2 GEMM: [N,128] @ [128,128] ==================
__global__ __launch_bounds__(256) void gemm_qkvs(
    const float* __restrict__ H,
    const float* __restrict__ Wq, const float* __restrict__ bq,
    const float* __restrict__ Wk, const float* __restrict__ bk,
    const float* __restrict__ Wv, const float* __restrict__ bv,
    const float* __restrict__ Ws, const float* __restrict__ bs,
    float* __restrict__ q, float* __restrict__ k, float* __restrict__ v,
    float* __restrict__ hs, int N) {
  int z = blockIdx.z;
  const float* W  = (z == 0) ? Wq : (z == 1) ? Wk : (z == 2) ? Wv : Ws;
  const float* bb = (z == 0) ? bq : (z == 1) ? bk : (z == 2) ? bv : bs;
  float* O        = (z == 0) ? q  : (z == 1) ? k  : (z == 2) ? v  : hs;

  __shared__ float hT[16][64];   // [k][row]
  __shared__ float Wl[16][128];  // [k][col]
  int tid = threadIdx.x;
  int tx = tid & 31;
  int ty = tid >> 5;
  int n0 = blockIdx.x * 64;

  float acc[8][4];
#pragma unroll
  for (int r = 0; r < 8; r++)
#pragma unroll
    for (int c = 0; c < 4; c++) acc[r][c] = 0.f;

  int lrow = tid >> 2;
  int lkk  = (tid & 3) * 4;
  int grow = min(n0 + lrow, N - 1);
  int wrow = tid >> 4;
  int wc   = (tid & 15) * 8;

  for (int k0 = 0; k0 < 128; k0 += 16) {
    float4 hv  = *(const float4*)&H[grow * 128 + k0 + lkk];
    float4 wv0 = *(const float4*)&W[(k0 + wrow) * 128 + wc];
    float4 wv1 = *(const float4*)&W[(k0 + wrow) * 128 + wc + 4];
    hT[lkk + 0][lrow] = hv.x; hT[lkk + 1][lrow] = hv.y;
    hT[lkk + 2][lrow] = hv.z; hT[lkk + 3][lrow] = hv.w;
    *(float4*)&Wl[wrow][wc]     = wv0;
    *(float4*)&Wl[wrow][wc + 4] = wv1;
    __syncthreads();
#pragma unroll
    for (int kk = 0; kk < 16; kk++) {
      float4 a0 = *(const float4*)&hT[kk][ty * 8];
      float4 a1 = *(const float4*)&hT[kk][ty * 8 + 4];
      float4 wv = *(const float4*)&Wl[kk][tx * 4];
      float ar[8] = {a0.x, a0.y, a0.z, a0.w, a1.x, a1.y, a1.z, a1.w};
      float wr[4] = {wv.x, wv.y, wv.z, wv.w};
#pragma unroll
      for (int r = 0; r < 8; r++)
#pragma unroll
        for (int c = 0; c < 4; c++) acc[r][c] = fmaf(ar[r], wr[c], acc[r][c]);
    }
    __syncthreads();
  }
  float4 bv4 = *(const float4*)&bb[tx * 4];
#pragma unroll
  for (int r = 0; r < 8; r++) {
    int n = n0 + ty * 8 + r;
    if (n < N) {
      float4 o;
      o.x = acc[r][0] + bv4.x; o.y = acc[r][1] + bv4.y;
      o.z = acc[r][2] + bv4.z; o.w = acc[r][3] + bv4.w;
      *(float4*)&O[n * 128 + tx * 4] = o;
    }
  }
}

// =========================== edge logits ================================
#define EPW 8
__global__ void edge_logits(const float* __restrict__ q, const float* __restrict__ kb,
                            const int* __restrict__ src, const int* __restrict__ dst,
                            const float* __restrict__ attr, const float* __restrict__ We,
                            float* __restrict__ logits, int E) {
  __shared__ float WeS[384];
  int tid = threadIdx.x;
  for (int i = tid; i < 384; i += 256) WeS[i] = We[i];
  __syncthreads();
  int lane = tid & 63;
  int wave = blockIdx.x * 4 + (tid >> 6);
  float w0 = WeS[2 * lane],       w1 = WeS[2 * lane + 1];
  float w2 = WeS[128 + 2 * lane], w3 = WeS[128 + 2 * lane + 1];
  float w4 = WeS[256 + 2 * lane], w5 = WeS[256 + 2 * lane + 1];
  int e0i = wave * EPW;
  int e1i = min(e0i + EPW, E);
  for (int e = e0i; e < e1i; e++) {
    int sj = src[e], dj = dst[e];
    float a0 = attr[e * 3 + 0], a1 = attr[e * 3 + 1], a2 = attr[e * 3 + 2];
    float2 qv = *(const float2*)&q[dj * 128 + 2 * lane];
    float2 kv = *(const float2*)&kb[sj * 128 + 2 * lane];
    float ee0 = a0 * w0 + a1 * w2 + a2 * w4;
    float ee1 = a0 * w1 + a1 * w3 + a2 * w5;
    float p = qv.x * (kv.x + ee0) + qv.y * (kv.y + ee1);
#pragma unroll
    for (int off = 32; off > 0; off >>= 1) p += __shfl_down(p, off);
    if (lane == 0) logits[e] = p * 0.08838834764831845f;  // 1/sqrt(128)
  }
}

// ================= node softmax + aggregate + skip + leaky ===============
__global__ void node_attn(const float* __restrict__ v, const float* __restrict__ logits,
                          const int* __restrict__ indptr, const int* __restrict__ eidx,
                          const int* __restrict__ src, const float* __restrict__ attr,
                          const float* __restrict__ We,
                          float* __restrict__ h, int N) {
  __shared__ float WeS[384];
  int tid = threadIdx.x;
  for (int i = tid; i < 384; i += 256) WeS[i] = We[i];
  __syncthreads();
  int lane = tid & 63;
  int n = blockIdx.x * 4 + (tid >> 6);
  if (n >= N) return;
  int beg = indptr[n], end = indptr[n + 1];
  float s0 = h[n * 128 + lane], s1 = h[n * 128 + 64 + lane];
  if (end > beg) {
    float m = -3.4e38f;
    for (int i = beg + lane; i < end; i += 64) m = fmaxf(m, logits[eidx[i]]);
#pragma unroll
    for (int off = 1; off < 64; off <<= 1) m = fmaxf(m, __shfl_xor(m, off));
    float w0 = WeS[lane],      w1 = WeS[128 + lane],      w2 = WeS[256 + lane];
    float w3 = WeS[64 + lane], w4 = WeS[192 + lane],      w5 = WeS[320 + lane];
    float acc0 = 0.f, acc1 = 0.f, den = 0.f;
    for (int i = beg; i < end; i++) {
      int e = eidx[i];
      float a = __expf(logits[e] - m);
      int sj = src[e];
      float a0 = attr[e * 3 + 0], a1 = attr[e * 3 + 1], a2 = attr[e * 3 + 2];
      float ee0 = a0 * w0 + a1 * w1 + a2 * w2;
      float ee1 = a0 * w3 + a1 * w4 + a2 * w5;
      acc0 += a * (v[sj * 128 + lane] + ee0);
      acc1 += a * (v[sj * 128 + 64 + lane] + ee1);
      den += a;
    }
    float inv = 1.f / den;
    s0 += acc0 * inv;
    s1 += acc1 * inv;
  }
  s0 = (s0 > 0.f) ? s0 : 0.01f * s0;
  s1 = (s1 > 0.f) ? s1 : 0.01f * s1;
  h[n * 128 + lane] = s0;
  h[n * 128 + 64 + lane] = s1;
}

// ======================= pool (batch is sorted) ==========================
__global__ void pool_kernel(const float* __restrict__ h, const int* __restrict__ batch,
                            float* __restrict__ gout, int N) {
  int c = threadIdx.x;  // 128
  int n0 = blockIdx.x * 128;
  if (n0 >= N) return;
  int n1 = min(n0 + 128, N);
  float acc = 0.f;
  int cur = batch[n0];
  for (int n = n0; n < n1; n++) {
    int b = batch[n];
    if (b != cur) { atomicAdd(&gout[cur * 128 + c], acc); acc = 0.f; cur = b; }
    acc += h[n * 128 + c];
  }
  atomicAdd(&gout[cur * 128 + c], acc);
}

// ===================== fused MLP head (one block / graph) ================
__global__ __launch_bounds__(256) void mlp_fused(
    const float* __restrict__ gp,
    const float* __restrict__ Wl0, const float* __restrict__ bl0,
    const float* __restrict__ Wl1, const float* __restrict__ bl1,
    const float* __restrict__ Wl2, const float* __restrict__ bl2,
    float* __restrict__ out) {
  int g = blockIdx.x;     // GDIM blocks
  int tid = threadIdx.x;  // 256
  __shared__ float xin[CDIM];
  __shared__ float h1[L0DIM];
  __shared__ float h2[L1DIM];
  __shared__ float r0s[4], r1s[4];
  if (tid < CDIM) xin[tid] = gp[g * CDIM + tid];
  __syncthreads();
  // stage 1: h1 = relu(xin @ Wl0 + bl0), 512 outputs, 2 per thread
  for (int c = tid; c < L0DIM; c += 256) {
    float a0 = 0.f, a1 = 0.f, a2 = 0.f, a3 = 0.f;
#pragma unroll 4
    for (int kk = 0; kk < CDIM; kk += 4) {
      a0 = fmaf(xin[kk + 0], Wl0[(kk + 0) * L0DIM + c], a0);
      a1 = fmaf(xin[kk + 1], Wl0[(kk + 1) * L0DIM + c], a1);
      a2 = fmaf(xin[kk + 2], Wl0[(kk + 2) * L0DIM + c], a2);
      a3 = fmaf(xin[kk + 3], Wl0[(kk + 3) * L0DIM + c], a3);
    }
    h1[c] = fmaxf((a0 + a1) + (a2 + a3) + bl0[c], 0.f);
  }
  __syncthreads();
  // stage 2: h2 = relu(h1 @ Wl1 + bl1), 256 outputs, 1 per thread
  {
    int c = tid;
    float a0 = 0.f, a1 = 0.f, a2 = 0.f, a3 = 0.f;
#pragma unroll 4
    for (int kk = 0; kk < L0DIM; kk += 4) {
      a0 = fmaf(h1[kk + 0], Wl1[(kk + 0) * L1DIM + c], a0);
      a1 = fmaf(h1[kk + 1], Wl1[(kk + 1) * L1DIM + c], a1);
      a2 = fmaf(h1[kk + 2], Wl1[(kk + 2) * L1DIM + c], a2);
      a3 = fmaf(h1[kk + 3], Wl1[(kk + 3) * L1DIM + c], a3);
    }
    h2[c] = fmaxf((a0 + a1) + (a2 + a3) + bl1[c], 0.f);
  }
  __syncthreads();
  // stage 3: out[g*2 + p] = h2 @ Wl2 + bl2  (K=256 reduced across block)
  float p0 = h2[tid] * Wl2[tid * 2 + 0];
  float p1 = h2[tid] * Wl2[tid * 2 + 1];
#pragma unroll
  for (int off = 32; off > 0; off >>= 1) {
    p0 += __shfl_down(p0, off);
    p1 += __shfl_down(p1, off);
  }
  int wv = tid >> 6, ln = tid & 63;
  if (ln == 0) { r0s[wv] = p0; r1s[wv] = p1; }
  __syncthreads();
  if (tid == 0) out[g * 2 + 0] = r0s[0] + r0s[1] + r0s[2] + r0s[3] + bl2[0];
  if (tid == 1) out[g * 2 + 1] = r1s[0] + r1s[1] + r1s[2] + r1s[3] + bl2[1];
}

// ============================== launch ==================================
extern "C" void kernel_launch(void* const* d_in, const int* in_sizes, int n_in,
                              void* d_out, int out_size, void* d_ws, size_t ws_size,
                              hipStream_t stream) {
  const int N = N_NODES, E = N_EDGES;
  const float* x    = (const float*)d_in[0];
  const int*   ei   = (const int*)d_in[1];
  const float* attr = (const float*)d_in[2];
  const int*   batch= (const int*)d_in[3];
  const int* src = ei;
  const int* dst = ei + E;

  const float *Wq0 = (const float*)d_in[4],  *bq0 = (const float*)d_in[5];
  const float *Wk0 = (const float*)d_in[6],  *bk0 = (const float*)d_in[7];
  const float *Wv0 = (const float*)d_in[8],  *bv0 = (const float*)d_in[9];
  const float *We0 = (const float*)d_in[10];
  const float *Ws0 = (const float*)d_in[11], *bs0 = (const float*)d_in[12];
  const float *Wq1 = (const float*)d_in[13], *bq1 = (const float*)d_in[14];
  const float *Wk1 = (const float*)d_in[15], *bk1 = (const float*)d_in[16];
  const float *Wv1 = (const float*)d_in[17], *bv1 = (const float*)d_in[18];
  const float *We1 = (const float*)d_in[19];
  const float *Ws1 = (const float*)d_in[20], *bs1 = (const float*)d_in[21];
  const float *Wl0 = (const float*)d_in[22], *bl0 = (const float*)d_in[23];
  const float *Wl1 = (const float*)d_in[24], *bl1 = (const float*)d_in[25];
  const float *Wl2 = (const float*)d_in[26], *bl2 = (const float*)d_in[27];

  // --- workspace carve ---
  size_t off = 0;
  auto carve = [&](size_t bytes) {
    void* p = (char*)d_ws + off;
    off += (bytes + 255) & ~(size_t)255;
    return p;
  };
  float* hA     = (float*)carve((size_t)N * CDIM * 4);
  float* hB     = (float*)carve((size_t)N * CDIM * 4);
  float* qb     = (float*)carve((size_t)N * CDIM * 4);
  float* kb     = (float*)carve((size_t)N * CDIM * 4);
  float* vb     = (float*)carve((size_t)N * CDIM * 4);
  float* logits = (float*)carve((size_t)E * 4);
  int*   indptr = (int*)carve((size_t)(N + 1) * 4);
  int*   eidx   = (int*)carve((size_t)E * 4);
  int*   counts = (int*)carve((size_t)N * 4);
  int*   cursor = (int*)carve((size_t)N * 4);
  int*   excl   = (int*)carve((size_t)N * 4);
  int*   bsums  = (int*)carve((size_t)64 * 4);
  float* gp     = (float*)carve((size_t)GDIM * CDIM * 4);

  hipMemsetAsync(counts, 0, (size_t)N * 4, stream);
  hipMemsetAsync(cursor, 0, (size_t)N * 4, stream);
  hipMemsetAsync(gp, 0, (size_t)GDIM * CDIM * 4, stream);

  // CSR build (dst-grouped), reused by all 3 layers
  int nscan = (N + 1023) / 1024;  // 49
  hist_kernel<<<(E + 255) / 256, 256, 0, stream>>>(dst, counts, E);
  scan_blocks<<<nscan, 1024, 0, stream>>>(counts, excl, bsums, N);
  scan_sums<<<1, 64, 0, stream>>>(bsums, nscan);
  scan_add<<<nscan, 1024, 0, stream>>>(excl, bsums, indptr, N, E);
  scatter_kernel<<<(E + 255) / 256, 256, 0, stream>>>(dst, indptr, cursor, eidx, E);

  int elBlocks = (E / EPW + 3) / 4;
  int naBlocks = (N + 3) / 4;

  // ---- layer 0 (din=4) ----
  l0_qkvs<<<(N * 128 + 255) / 256, 256, 0, stream>>>(
      x, Wq0, bq0, Wk0, bk0, Wv0, bv0, Ws0, bs0, qb, kb, vb, hA, N);
  edge_logits<<<elBlocks, 256, 0, stream>>>(qb, kb, src, dst, attr, We0, logits, E);
  node_attn<<<naBlocks, 256, 0, stream>>>(vb, logits, indptr, eidx, src, attr, We0, hA, N);

  // ---- layer 1 (shared weights) ----
  gemm_qkvs<<<dim3((N + 63) / 64, 1, 4), 256, 0, stream>>>(
      hA, Wq1, bq1, Wk1, bk1, Wv1, bv1, Ws1, bs1, qb, kb, vb, hB, N);
  edge_logits<<<elBlocks, 256, 0, stream>>>(qb, kb, src, dst, attr, We1, logits, E);
  node_attn<<<naBlocks, 256, 0, stream>>>(vb, logits, indptr, eidx, src, attr, We1, hB, N);

  // ---- layer 2 (same weights again) ----
  gemm_qkvs<<<dim3((N + 63) / 64, 1, 4), 256, 0, stream>>>(
      hB, Wq1, bq1, Wk1, bk1, Wv1, bv1, Ws1, bs1, qb, kb, vb, hA, N);
  edge_logits<<<elBlocks, 256, 0, stream>>>(qb, kb, src, dst, attr, We1, logits, E);
  node_attn<<<naBlocks, 256, 0, stream>>>(vb, logits, indptr, eidx, src, attr, We1, hA, N);

  // ---- pool + fused MLP ----
  pool_kernel<<<(N + 127) / 128, 128, 0, stream>>>(hA, batch, gp, N);
  mlp_fused<<<GDIM, 256, 0, stream>>>(gp, Wl0, bl0, Wl1, bl1, Wl2, bl2, (float*)d_out);
}

// Round 3
// 900.221 us; speedup vs baseline: 1.6881x; 1.4185x over previous
//
#include <hip/hip_runtime.h>
#include <math.h>

#define N_NODES 50000
#define N_EDGES 800000
#define CDIM    128
#define GDIM    128
#define L0DIM   512
#define L1DIM   256

typedef unsigned int uint;
typedef unsigned short ushort;

__device__ inline ushort f2bf(float f) {
  uint u = __float_as_uint(f);
  uint r = (u + 0x7fffu + ((u >> 16) & 1u)) >> 16;
  return (ushort)r;
}

// ============================ CSR build =================================
__global__ void hist_kernel(const int* __restrict__ dst, int* counts, int E) {
  int e = blockIdx.x * 256 + threadIdx.x;
  if (e < E) atomicAdd(&counts[dst[e]], 1);
}

__global__ void scan_blocks(const int* __restrict__ counts, int* excl, int* bsums, int N) {
  __shared__ int s[1024];
  int tid = threadIdx.x;
  int i = blockIdx.x * 1024 + tid;
  int v = (i < N) ? counts[i] : 0;
  s[tid] = v;
  __syncthreads();
  for (int off = 1; off < 1024; off <<= 1) {
    int t = (tid >= off) ? s[tid - off] : 0;
    __syncthreads();
    s[tid] += t;
    __syncthreads();
  }
  if (i < N) excl[i] = s[tid] - v;
  if (tid == 1023) bsums[blockIdx.x] = s[1023];
}

__global__ void scan_sums(int* bsums, int nb) {
  if (threadIdx.x == 0) {
    int run = 0;
    for (int b = 0; b < nb; b++) { int t = bsums[b]; bsums[b] = run; run += t; }
  }
}

__global__ void scan_add(const int* __restrict__ excl, const int* __restrict__ bsums,
                         int* indptr, int N, int E) {
  int i = blockIdx.x * 1024 + threadIdx.x;
  if (i < N) indptr[i] = excl[i] + bsums[blockIdx.x];
  if (i == 0) indptr[N] = E;
}

// scatter + materialize CSR-ordered src and attr (sequential reads later)
__global__ void scatter2_kernel(const int* __restrict__ dst, const int* __restrict__ src,
                                const float* __restrict__ attr,
                                const int* __restrict__ indptr,
                                int* cursor, int* csr_src, float4* csr_attr, int E) {
  int e = blockIdx.x * 256 + threadIdx.x;
  if (e < E) {
    int d = dst[e];
    int pos = atomicAdd(&cursor[d], 1);
    int i = indptr[d] + pos;
    csr_src[i] = src[e];
    csr_attr[i] = make_float4(attr[e * 3 + 0], attr[e * 3 + 1], attr[e * 3 + 2], 0.f);
  }
}

// ===================== layer 0 (din=4) q/kv/skip ========================
__global__ void l0_qkvs(const float* __restrict__ x,
                        const float* __restrict__ Wq, const float* __restrict__ bq,
                        const float* __restrict__ Wk, const float* __restrict__ bk,
                        const float* __restrict__ Wv, const float* __restrict__ bv,
                        const float* __restrict__ Ws, const float* __restrict__ bs,
                        float* __restrict__ q, ushort* __restrict__ kvb,
                        float* __restrict__ hs, int N) {
  __shared__ float W[4][4][128];
  __shared__ float B[4][128];
  int tid = threadIdx.x;
  for (int i = tid; i < 4 * 128; i += 256) {
    W[0][i >> 7][i & 127] = Wq[i];
    W[1][i >> 7][i & 127] = Wk[i];
    W[2][i >> 7][i & 127] = Wv[i];
    W[3][i >> 7][i & 127] = Ws[i];
  }
  for (int i = tid; i < 128; i += 256) {
    B[0][i] = bq[i]; B[1][i] = bk[i]; B[2][i] = bv[i]; B[3][i] = bs[i];
  }
  __syncthreads();
  int gid = blockIdx.x * 256 + tid;
  int n = gid >> 7, c = gid & 127;
  if (n >= N) return;
  float x0 = x[n * 4 + 0], x1 = x[n * 4 + 1], x2 = x[n * 4 + 2], x3 = x[n * 4 + 3];
  float qv = x0 * W[0][0][c] + x1 * W[0][1][c] + x2 * W[0][2][c] + x3 * W[0][3][c] + B[0][c];
  float kv = x0 * W[1][0][c] + x1 * W[1][1][c] + x2 * W[1][2][c] + x3 * W[1][3][c] + B[1][c];
  float vv = x0 * W[2][0][c] + x1 * W[2][1][c] + x2 * W[2][2][c] + x3 * W[2][3][c] + B[2][c];
  float sv = x0 * W[3][0][c] + x1 * W[3][1][c] + x2 * W[3][2][c] + x3 * W[3][3][c] + B[3][c];
  q[n * 128 + c] = qv;
  kvb[(size_t)n * 256 + c]       = f2bf(kv);
  kvb[(size_t)n * 256 + 128 + c] = f2bf(vv);
  hs[n * 128 + c] = sv;
}

// ================= layers 1-2 GEMM: [N,128] @ [128,128] ==================
// z: 0=q (fp32), 1=k (bf16 into kv[:,0:128]), 2=v (bf16 into kv[:,128:256]), 3=skip (fp32)
__global__ __launch_bounds__(256) void gemm_qkvs(
    const float* __restrict__ H,
    const float* __restrict__ Wq, const float* __restrict__ bq,
    const float* __restrict__ Wk, const float* __restrict__ bk,
    const float* __restrict__ Wv, const float* __restrict__ bv,
    const float* __restrict__ Ws, const float* __restrict__ bs,
    float* __restrict__ q, ushort* __restrict__ kvb,
    float* __restrict__ hs, int N) {
  int z = blockIdx.z;
  const float* W  = (z == 0) ? Wq : (z == 1) ? Wk : (z == 2) ? Wv : Ws;
  const float* bb = (z == 0) ? bq : (z == 1) ? bk : (z == 2) ? bv : bs;

  __shared__ float hT[16][64];
  __shared__ float Wl[16][128];
  int tid = threadIdx.x;
  int tx = tid & 31;
  int ty = tid >> 5;
  int n0 = blockIdx.x * 64;

  float acc[8][4];
#pragma unroll
  for (int r = 0; r < 8; r++)
#pragma unroll
    for (int c = 0; c < 4; c++) acc[r][c] = 0.f;

  int lrow = tid >> 2;
  int lkk  = (tid & 3) * 4;
  int grow = min(n0 + lrow, N - 1);
  int wrow = tid >> 4;
  int wc   = (tid & 15) * 8;

  for (int k0 = 0; k0 < 128; k0 += 16) {
    float4 hv  = *(const float4*)&H[grow * 128 + k0 + lkk];
    float4 wv0 = *(const float4*)&W[(k0 + wrow) * 128 + wc];
    float4 wv1 = *(const float4*)&W[(k0 + wrow) * 128 + wc + 4];
    hT[lkk + 0][lrow] = hv.x; hT[lkk + 1][lrow] = hv.y;
    hT[lkk + 2][lrow] = hv.z; hT[lkk + 3][lrow] = hv.w;
    *(float4*)&Wl[wrow][wc]     = wv0;
    *(float4*)&Wl[wrow][wc + 4] = wv1;
    __syncthreads();
#pragma unroll
    for (int kk = 0; kk < 16; kk++) {
      float4 a0 = *(const float4*)&hT[kk][ty * 8];
      float4 a1 = *(const float4*)&hT[kk][ty * 8 + 4];
      float4 wv = *(const float4*)&Wl[kk][tx * 4];
      float ar[8] = {a0.x, a0.y, a0.z, a0.w, a1.x, a1.y, a1.z, a1.w};
      float wr[4] = {wv.x, wv.y, wv.z, wv.w};
#pragma unroll
      for (int r = 0; r < 8; r++)
#pragma unroll
        for (int c = 0; c < 4; c++) acc[r][c] = fmaf(ar[r], wr[c], acc[r][c]);
    }
    __syncthreads();
  }
  float4 bv4 = *(const float4*)&bb[tx * 4];
#pragma unroll
  for (int r = 0; r < 8; r++) {
    int n = n0 + ty * 8 + r;
    if (n >= N) continue;
    float o0 = acc[r][0] + bv4.x, o1 = acc[r][1] + bv4.y;
    float o2 = acc[r][2] + bv4.z, o3 = acc[r][3] + bv4.w;
    if (z == 0) {
      *(float4*)&q[n * 128 + tx * 4] = make_float4(o0, o1, o2, o3);
    } else if (z == 3) {
      *(float4*)&hs[n * 128 + tx * 4] = make_float4(o0, o1, o2, o3);
    } else {
      uint2 pk;
      pk.x = (uint)f2bf(o0) | ((uint)f2bf(o1) << 16);
      pk.y = (uint)f2bf(o2) | ((uint)f2bf(o3) << 16);
      *(uint2*)&kvb[(size_t)n * 256 + ((z == 2) ? 128 : 0) + tx * 4] = pk;
    }
  }
}

// ====== fused attention: online softmax over CSR in-edges, 1 wave/node ======
// kv table bf16 [N][256] = k|v. q fp32. h holds skip on entry, final h on exit.
__global__ __launch_bounds__(256) void attn_fused(
    const float* __restrict__ q, const ushort* __restrict__ kv,
    const int* __restrict__ indptr, const int* __restrict__ csr_src,
    const float4* __restrict__ csr_attr, const float* __restrict__ We,
    float* __restrict__ h, int N) {
  __shared__ float WeS[384];
  int tid = threadIdx.x;
  for (int i = tid; i < 384; i += 256) WeS[i] = We[i];
  __syncthreads();
  int lane = tid & 63;
  int n = blockIdx.x * 4 + (tid >> 6);
  if (n >= N) return;
  int c0 = 2 * lane, c1 = 2 * lane + 1;
  float w00 = WeS[c0],       w01 = WeS[c1];
  float w10 = WeS[128 + c0], w11 = WeS[128 + c1];
  float w20 = WeS[256 + c0], w21 = WeS[256 + c1];

  int beg = indptr[n], end = indptr[n + 1];
  float2 sk = *(const float2*)&h[n * 128 + c0];  // skip
  if (end > beg) {
    float2 qv = *(const float2*)&q[n * 128 + c0];
    float m = -3.4e38f, d = 0.f, acc0 = 0.f, acc1 = 0.f;
    const uint* kvw = (const uint*)kv;  // 128 uints per node row
    for (int i = beg; i < end; i += 4) {
      int cnt = end - i; cnt = (cnt > 4) ? 4 : cnt;
      int sjs[4]; float4 ats[4]; uint kr[4], vr[4];
#pragma unroll
      for (int t = 0; t < 4; t++)
        if (t < cnt) { sjs[t] = csr_src[i + t]; ats[t] = csr_attr[i + t]; }
#pragma unroll
      for (int t = 0; t < 4; t++)
        if (t < cnt) {
          const uint* kp = kvw + (size_t)sjs[t] * 128;
          kr[t] = kp[lane];
          vr[t] = kp[64 + lane];
        }
#pragma unroll
      for (int t = 0; t < 4; t++)
        if (t < cnt) {
          float ee0 = ats[t].x * w00 + ats[t].y * w10 + ats[t].z * w20;
          float ee1 = ats[t].x * w01 + ats[t].y * w11 + ats[t].z * w21;
          float k0 = __uint_as_float(kr[t] << 16);
          float k1 = __uint_as_float(kr[t] & 0xffff0000u);
          float v0 = __uint_as_float(vr[t] << 16);
          float v1 = __uint_as_float(vr[t] & 0xffff0000u);
          float p = qv.x * (k0 + ee0) + qv.y * (k1 + ee1);
#pragma unroll
          for (int off = 1; off < 64; off <<= 1) p += __shfl_xor(p, off);
          float l = p * 0.08838834764831845f;  // 1/sqrt(128)
          float nm = fmaxf(m, l);
          float sf = __expf(m - nm);
          float a = __expf(l - nm);
          d = d * sf + a;
          acc0 = acc0 * sf + a * (v0 + ee0);
          acc1 = acc1 * sf + a * (v1 + ee1);
          m = nm;
        }
    }
    float inv = 1.f / d;
    sk.x += acc0 * inv;
    sk.y += acc1 * inv;
  }
  sk.x = (sk.x > 0.f) ? sk.x : 0.01f * sk.x;
  sk.y = (sk.y > 0.f) ? sk.y : 0.01f * sk.y;
  *(float2*)&h[n * 128 + c0] = sk;
}

// ======================= pool (batch is sorted) ==========================
__global__ void pool_kernel(const float* __restrict__ h, const int* __restrict__ batch,
                            float* __restrict__ gout, int N) {
  int c = threadIdx.x;  // 128
  int n0 = blockIdx.x * 128;
  if (n0 >= N) return;
  int n1 = min(n0 + 128, N);
  float acc = 0.f;
  int cur = batch[n0];
  for (int n = n0; n < n1; n++) {
    int b = batch[n];
    if (b != cur) { atomicAdd(&gout[cur * 128 + c], acc); acc = 0.f; cur = b; }
    acc += h[n * 128 + c];
  }
  atomicAdd(&gout[cur * 128 + c], acc);
}

// ===================== fused MLP head (one block / graph) ================
__global__ __launch_bounds__(256) void mlp_fused(
    const float* __restrict__ gp,
    const float* __restrict__ Wl0, const float* __restrict__ bl0,
    const float* __restrict__ Wl1, const float* __restrict__ bl1,
    const float* __restrict__ Wl2, const float* __restrict__ bl2,
    float* __restrict__ out) {
  int g = blockIdx.x;
  int tid = threadIdx.x;
  __shared__ float xin[CDIM];
  __shared__ float h1[L0DIM];
  __shared__ float h2[L1DIM];
  __shared__ float r0s[4], r1s[4];
  if (tid < CDIM) xin[tid] = gp[g * CDIM + tid];
  __syncthreads();
  for (int c = tid; c < L0DIM; c += 256) {
    float a0 = 0.f, a1 = 0.f, a2 = 0.f, a3 = 0.f;
#pragma unroll 4
    for (int kk = 0; kk < CDIM; kk += 4) {
      a0 = fmaf(xin[kk + 0], Wl0[(kk + 0) * L0DIM + c], a0);
      a1 = fmaf(xin[kk + 1], Wl0[(kk + 1) * L0DIM + c], a1);
      a2 = fmaf(xin[kk + 2], Wl0[(kk + 2) * L0DIM + c], a2);
      a3 = fmaf(xin[kk + 3], Wl0[(kk + 3) * L0DIM + c], a3);
    }
    h1[c] = fmaxf((a0 + a1) + (a2 + a3) + bl0[c], 0.f);
  }
  __syncthreads();
  {
    int c = tid;
    float a0 = 0.f, a1 = 0.f, a2 = 0.f, a3 = 0.f;
#pragma unroll 4
    for (int kk = 0; kk < L0DIM; kk += 4) {
      a0 = fmaf(h1[kk + 0], Wl1[(kk + 0) * L1DIM + c], a0);
      a1 = fmaf(h1[kk + 1], Wl1[(kk + 1) * L1DIM + c], a1);
      a2 = fmaf(h1[kk + 2], Wl1[(kk + 2) * L1DIM + c], a2);
      a3 = fmaf(h1[kk + 3], Wl1[(kk + 3) * L1DIM + c], a3);
    }
    h2[c] = fmaxf((a0 + a1) + (a2 + a3) + bl1[c], 0.f);
  }
  __syncthreads();
  float p0 = h2[tid] * Wl2[tid * 2 + 0];
  float p1 = h2[tid] * Wl2[tid * 2 + 1];
#pragma unroll
  for (int off = 32; off > 0; off >>= 1) {
    p0 += __shfl_down(p0, off);
    p1 += __shfl_down(p1, off);
  }
  int wv = tid >> 6, ln = tid & 63;
  if (ln == 0) { r0s[wv] = p0; r1s[wv] = p1; }
  __syncthreads();
  if (tid == 0) out[g * 2 + 0] = r0s[0] + r0s[1] + r0s[2] + r0s[3] + bl2[0];
  if (tid == 1) out[g * 2 + 1] = r1s[0] + r1s[1] + r1s[2] + r1s[3] + bl2[1];
}

// ============================== launch ==================================
extern "C" void kernel_launch(void* const* d_in, const int* in_sizes, int n_in,
                              void* d_out, int out_size, void* d_ws, size_t ws_size,
                              hipStream_t stream) {
  const int N = N_NODES, E = N_EDGES;
  const float* x    = (const float*)d_in[0];
  const int*   ei   = (const int*)d_in[1];
  const float* attr = (const float*)d_in[2];
  const int*   batch= (const int*)d_in[3];
  const int* src = ei;
  const int* dst = ei + E;

  const float *Wq0 = (const float*)d_in[4],  *bq0 = (const float*)d_in[5];
  const float *Wk0 = (const float*)d_in[6],  *bk0 = (const float*)d_in[7];
  const float *Wv0 = (const float*)d_in[8],  *bv0 = (const float*)d_in[9];
  const float *We0 = (const float*)d_in[10];
  const float *Ws0 = (const float*)d_in[11], *bs0 = (const float*)d_in[12];
  const float *Wq1 = (const float*)d_in[13], *bq1 = (const float*)d_in[14];
  const float *Wk1 = (const float*)d_in[15], *bk1 = (const float*)d_in[16];
  const float *Wv1 = (const float*)d_in[17], *bv1 = (const float*)d_in[18];
  const float *We1 = (const float*)d_in[19];
  const float *Ws1 = (const float*)d_in[20], *bs1 = (const float*)d_in[21];
  const float *Wl0 = (const float*)d_in[22], *bl0 = (const float*)d_in[23];
  const float *Wl1 = (const float*)d_in[24], *bl1 = (const float*)d_in[25];
  const float *Wl2 = (const float*)d_in[26], *bl2 = (const float*)d_in[27];

  size_t off = 0;
  auto carve = [&](size_t bytes) {
    void* p = (char*)d_ws + off;
    off += (bytes + 255) & ~(size_t)255;
    return p;
  };
  float*  hA       = (float*)carve((size_t)N * CDIM * 4);
  float*  hB       = (float*)carve((size_t)N * CDIM * 4);
  float*  qb       = (float*)carve((size_t)N * CDIM * 4);
  ushort* kvb      = (ushort*)carve((size_t)N * 256 * 2);
  int*    indptr   = (int*)carve((size_t)(N + 1) * 4);
  int*    csr_src  = (int*)carve((size_t)E * 4);
  float4* csr_attr = (float4*)carve((size_t)E * 16);
  int*    counts   = (int*)carve((size_t)N * 4);
  int*    cursor   = (int*)carve((size_t)N * 4);
  int*    excl     = (int*)carve((size_t)N * 4);
  int*    bsums    = (int*)carve((size_t)64 * 4);
  float*  gp       = (float*)carve((size_t)GDIM * CDIM * 4);

  hipMemsetAsync(counts, 0, (size_t)N * 4, stream);
  hipMemsetAsync(cursor, 0, (size_t)N * 4, stream);
  hipMemsetAsync(gp, 0, (size_t)GDIM * CDIM * 4, stream);

  int nscan = (N + 1023) / 1024;
  hist_kernel<<<(E + 255) / 256, 256, 0, stream>>>(dst, counts, E);
  scan_blocks<<<nscan, 1024, 0, stream>>>(counts, excl, bsums, N);
  scan_sums<<<1, 64, 0, stream>>>(bsums, nscan);
  scan_add<<<nscan, 1024, 0, stream>>>(excl, bsums, indptr, N, E);
  scatter2_kernel<<<(E + 255) / 256, 256, 0, stream>>>(dst, src, attr, indptr, cursor,
                                                       csr_src, csr_attr, E);

  int naBlocks = (N + 3) / 4;

  // ---- layer 0 (din=4) ----
  l0_qkvs<<<(N * 128 + 255) / 256, 256, 0, stream>>>(
      x, Wq0, bq0, Wk0, bk0, Wv0, bv0, Ws0, bs0, qb, kvb, hA, N);
  attn_fused<<<naBlocks, 256, 0, stream>>>(qb, kvb, indptr, csr_src, csr_attr, We0, hA, N);

  // ---- layer 1 (shared weights) ----
  gemm_qkvs<<<dim3((N + 63) / 64, 1, 4), 256, 0, stream>>>(
      hA, Wq1, bq1, Wk1, bk1, Wv1, bv1, Ws1, bs1, qb, kvb, hB, N);
  attn_fused<<<naBlocks, 256, 0, stream>>>(qb, kvb, indptr, csr_src, csr_attr, We1, hB, N);

  // ---- layer 2 (same weights) ----
  gemm_qkvs<<<dim3((N + 63) / 64, 1, 4), 256, 0, stream>>>(
      hB, Wq1, bq1, Wk1, bk1, Wv1, bv1, Ws1, bs1, qb, kvb, hA, N);
  attn_fused<<<naBlocks, 256, 0, stream>>>(qb, kvb, indptr, csr_src, csr_attr, We1, hA, N);

  // ---- pool + fused MLP ----
  pool_kernel<<<(N + 127) / 128, 128, 0, stream>>>(hA, batch, gp, N);
  mlp_fused<<<GDIM, 256, 0, stream>>>(gp, Wl0, bl0, Wl1, bl1, Wl2, bl2, (float*)d_out);
}

// Round 4
// 640.080 us; speedup vs baseline: 2.3742x; 1.4064x over previous
//
#include <hip/hip_runtime.h>
#include <math.h>

#define N_NODES 50000
#define N_EDGES 800000
#define CDIM    128
#define GDIM    128
#define L0DIM   512
#define L1DIM   256

typedef unsigned int uint;
typedef unsigned short ushort;
typedef __attribute__((ext_vector_type(8))) short short8;
typedef __attribute__((ext_vector_type(4))) float f32x4;

__device__ inline ushort f2bf(float f) {
  uint u = __float_as_uint(f);
  uint r = (u + 0x7fffu + ((u >> 16) & 1u)) >> 16;
  return (ushort)r;
}
__device__ inline float bflo(uint u) { return __uint_as_float(u << 16); }
__device__ inline float bfhi(uint u) { return __uint_as_float(u & 0xffff0000u); }

// ============================ CSR build =================================
__global__ void hist_kernel(const int* __restrict__ dst, int* counts, int E) {
  int e = blockIdx.x * 256 + threadIdx.x;
  if (e < E) atomicAdd(&counts[dst[e]], 1);
}

__global__ void scan_blocks(const int* __restrict__ counts, int* excl, int* bsums, int N) {
  __shared__ int s[1024];
  int tid = threadIdx.x;
  int i = blockIdx.x * 1024 + tid;
  int v = (i < N) ? counts[i] : 0;
  s[tid] = v;
  __syncthreads();
  for (int off = 1; off < 1024; off <<= 1) {
    int t = (tid >= off) ? s[tid - off] : 0;
    __syncthreads();
    s[tid] += t;
    __syncthreads();
  }
  if (i < N) excl[i] = s[tid] - v;
  if (tid == 1023) bsums[blockIdx.x] = s[1023];
}

__global__ void scan_sums(int* bsums, int nb) {
  if (threadIdx.x == 0) {
    int run = 0;
    for (int b = 0; b < nb; b++) { int t = bsums[b]; bsums[b] = run; run += t; }
  }
}

__global__ void scan_add(const int* __restrict__ excl, const int* __restrict__ bsums,
                         int* indptr, int N, int E) {
  int i = blockIdx.x * 1024 + threadIdx.x;
  if (i < N) indptr[i] = excl[i] + bsums[blockIdx.x];
  if (i == 0) indptr[N] = E;
}

__global__ void scatter2_kernel(const int* __restrict__ dst, const int* __restrict__ src,
                                const float* __restrict__ attr,
                                const int* __restrict__ indptr,
                                int* cursor, int* csr_src, float4* csr_attr, int E) {
  int e = blockIdx.x * 256 + threadIdx.x;
  if (e < E) {
    int d = dst[e];
    int pos = atomicAdd(&cursor[d], 1);
    int i = indptr[d] + pos;
    csr_src[i] = src[e];
    csr_attr[i] = make_float4(attr[e * 3 + 0], attr[e * 3 + 1], attr[e * 3 + 2], 0.f);
  }
}

// ===================== layer 0 (din=4) q/kv/skip ========================
__global__ void l0_qkvs(const float* __restrict__ x,
                        const float* __restrict__ Wq, const float* __restrict__ bq,
                        const float* __restrict__ Wk, const float* __restrict__ bk,
                        const float* __restrict__ Wv, const float* __restrict__ bv,
                        const float* __restrict__ Ws, const float* __restrict__ bs,
                        float* __restrict__ q, ushort* __restrict__ kvb,
                        float* __restrict__ hs, int N) {
  __shared__ float W[4][4][128];
  __shared__ float B[4][128];
  int tid = threadIdx.x;
  for (int i = tid; i < 4 * 128; i += 256) {
    W[0][i >> 7][i & 127] = Wq[i];
    W[1][i >> 7][i & 127] = Wk[i];
    W[2][i >> 7][i & 127] = Wv[i];
    W[3][i >> 7][i & 127] = Ws[i];
  }
  for (int i = tid; i < 128; i += 256) {
    B[0][i] = bq[i]; B[1][i] = bk[i]; B[2][i] = bv[i]; B[3][i] = bs[i];
  }
  __syncthreads();
  int gid = blockIdx.x * 256 + tid;
  int n = gid >> 7, c = gid & 127;
  if (n >= N) return;
  float x0 = x[n * 4 + 0], x1 = x[n * 4 + 1], x2 = x[n * 4 + 2], x3 = x[n * 4 + 3];
  float qv = x0 * W[0][0][c] + x1 * W[0][1][c] + x2 * W[0][2][c] + x3 * W[0][3][c] + B[0][c];
  float kv = x0 * W[1][0][c] + x1 * W[1][1][c] + x2 * W[1][2][c] + x3 * W[1][3][c] + B[1][c];
  float vv = x0 * W[2][0][c] + x1 * W[2][1][c] + x2 * W[2][2][c] + x3 * W[2][3][c] + B[2][c];
  float sv = x0 * W[3][0][c] + x1 * W[3][1][c] + x2 * W[3][2][c] + x3 * W[3][3][c] + B[3][c];
  q[n * 128 + c] = qv;
  kvb[(size_t)n * 256 + c]       = f2bf(kv);
  kvb[(size_t)n * 256 + 128 + c] = f2bf(vv);
  hs[n * 128 + c] = sv;
}

// ============== W -> bf16 transposed: wt[z][c][k] = W_z[k][c] =============
__global__ void prep_w(const float* __restrict__ Wq, const float* __restrict__ Wk,
                       const float* __restrict__ Wv, const float* __restrict__ Ws,
                       ushort* __restrict__ wt) {
  int idx = blockIdx.x * 256 + threadIdx.x;  // 4*16384
  int z = idx >> 14, rem = idx & 16383;
  int k_ = rem >> 7, c_ = rem & 127;
  const float* W = (z == 0) ? Wq : (z == 1) ? Wk : (z == 2) ? Wv : Ws;
  wt[z * 16384 + c_ * 128 + k_] = f2bf(W[k_ * 128 + c_]);
}

// ============ layers 1-2 GEMM via MFMA: [N,128] @ [128,128] ==============
// z: 0=q(fp32) 1=k(bf16) 2=v(bf16) 3=skip(fp32). 64 rows x 128 cols / block.
#define LDA 136   // padded bf16 leading dim (+8 breaks 256B-stride bank alias)
__global__ __launch_bounds__(256) void gemm_mfma(
    const float* __restrict__ H, const ushort* __restrict__ wtg,
    const float* __restrict__ bq, const float* __restrict__ bk,
    const float* __restrict__ bv, const float* __restrict__ bs,
    float* __restrict__ q, ushort* __restrict__ kvb,
    float* __restrict__ hs, int N) {
  int z = blockIdx.z;
  const float* bb = (z == 0) ? bq : (z == 1) ? bk : (z == 2) ? bv : bs;
  __shared__ ushort Alds[64 * LDA];
  __shared__ ushort Wlds[128 * LDA];
  int tid = threadIdx.x;
  int n0 = blockIdx.x * 64;

  // stage W^T bf16 (16384 elems = 8192 uints)
  {
    const uint* wg = (const uint*)(wtg + z * 16384);
    uint* wl = (uint*)Wlds;
    for (int i = tid; i < 8192; i += 256) {
      int c_ = i >> 6, kp = i & 63;
      wl[c_ * (LDA / 2) + kp] = wg[c_ * 64 + kp];
    }
  }
  // stage H tile -> bf16 (64 rows x 128)
  {
    uint* al = (uint*)Alds;
    for (int i = tid; i < 4096; i += 256) {
      int r = i >> 6, kp = i & 63;
      int grow = n0 + r; grow = (grow < N) ? grow : (N - 1);
      float2 hv = *(const float2*)&H[(size_t)grow * 128 + 2 * kp];
      al[r * (LDA / 2) + kp] = (uint)f2bf(hv.x) | ((uint)f2bf(hv.y) << 16);
    }
  }
  __syncthreads();

  int w = tid >> 6, lane = tid & 63;
  int m_ = lane & 15, quad = lane >> 4;
  f32x4 acc[8];
#pragma unroll
  for (int ct = 0; ct < 8; ct++) acc[ct] = 0.f;

#pragma unroll
  for (int kc = 0; kc < 4; kc++) {
    short8 af = *(const short8*)&Alds[(w * 16 + m_) * LDA + kc * 32 + quad * 8];
#pragma unroll
    for (int ct = 0; ct < 8; ct++) {
      short8 bf = *(const short8*)&Wlds[(ct * 16 + m_) * LDA + kc * 32 + quad * 8];
      acc[ct] = __builtin_amdgcn_mfma_f32_16x16x32_bf16(af, bf, acc[ct], 0, 0, 0);
    }
  }

  // epilogue: D row = quad*4+reg, col = ct*16 + m_
#pragma unroll
  for (int ct = 0; ct < 8; ct++) {
    int col = ct * 16 + m_;
    float bcol = bb[col];
#pragma unroll
    for (int reg = 0; reg < 4; reg++) {
      int n = n0 + w * 16 + quad * 4 + reg;
      if (n < N) {
        float o = acc[ct][reg] + bcol;
        if (z == 0)      q[(size_t)n * 128 + col] = o;
        else if (z == 3) hs[(size_t)n * 128 + col] = o;
        else             kvb[(size_t)n * 256 + ((z == 2) ? 128 : 0) + col] = f2bf(o);
      }
    }
  }
}

// ====== fused attention: online softmax, 4 edges/wave (16-lane groups) ======
__global__ __launch_bounds__(256) void attn_fused(
    const float* __restrict__ q, const ushort* __restrict__ kv,
    const int* __restrict__ indptr, const int* __restrict__ csr_src,
    const float4* __restrict__ csr_attr, const float* __restrict__ We,
    float* __restrict__ h, int N) {
  __shared__ float WeS[384];
  int tid = threadIdx.x;
  for (int i = tid; i < 384; i += 256) WeS[i] = We[i];
  __syncthreads();
  int lane = tid & 63;
  int n = blockIdx.x * 4 + (tid >> 6);
  if (n >= N) return;
  int g = lane >> 4, gl = lane & 15;
  int c = gl * 8;  // 8 channels per lane
  float w0[8], w1[8], w2[8];
#pragma unroll
  for (int j = 0; j < 8; j++) {
    w0[j] = WeS[c + j]; w1[j] = WeS[128 + c + j]; w2[j] = WeS[256 + c + j];
  }
  float4 qa = *(const float4*)&q[(size_t)n * 128 + c];
  float4 qb4 = *(const float4*)&q[(size_t)n * 128 + c + 4];
  float qv[8] = {qa.x, qa.y, qa.z, qa.w, qb4.x, qb4.y, qb4.z, qb4.w};
  float4 sk0 = *(const float4*)&h[(size_t)n * 128 + c];
  float4 sk1 = *(const float4*)&h[(size_t)n * 128 + c + 4];
  int beg = indptr[n], end = indptr[n + 1];

  if (end > beg) {
    float m = -3.4e38f, d = 0.f;
    float acc[8];
#pragma unroll
    for (int j = 0; j < 8; j++) acc[j] = 0.f;
    const uint* kvw = (const uint*)kv;
    int i = beg + g;
    int sj = 0; float4 at = make_float4(0.f, 0.f, 0.f, 0.f);
    if (i < end) { sj = csr_src[i]; at = csr_attr[i]; }
    for (; i < end; i += 4) {
      int sjc = sj; float4 atc = at;
      int inx = i + 4;
      if (inx < end) { sj = csr_src[inx]; at = csr_attr[inx]; }
      const uint4* kp = (const uint4*)(kvw + (size_t)sjc * 128);
      uint4 kr = kp[gl];
      uint4 vr = kp[16 + gl];
      float kx[8], vx[8];
      kx[0] = bflo(kr.x); kx[1] = bfhi(kr.x); kx[2] = bflo(kr.y); kx[3] = bfhi(kr.y);
      kx[4] = bflo(kr.z); kx[5] = bfhi(kr.z); kx[6] = bflo(kr.w); kx[7] = bfhi(kr.w);
      vx[0] = bflo(vr.x); vx[1] = bfhi(vr.x); vx[2] = bflo(vr.y); vx[3] = bfhi(vr.y);
      vx[4] = bflo(vr.z); vx[5] = bfhi(vr.z); vx[6] = bflo(vr.w); vx[7] = bfhi(vr.w);
      float p = 0.f;
      float u_[8];
#pragma unroll
      for (int j = 0; j < 8; j++) {
        float ee = atc.x * w0[j] + atc.y * w1[j] + atc.z * w2[j];
        p = fmaf(qv[j], kx[j] + ee, p);
        u_[j] = vx[j] + ee;
      }
      // reduce over the 16-lane group
      p += __shfl_xor(p, 1); p += __shfl_xor(p, 2);
      p += __shfl_xor(p, 4); p += __shfl_xor(p, 8);
      float l = p * 0.08838834764831845f;  // 1/sqrt(128)
      float nm = fmaxf(m, l);
      float sf = __expf(m - nm);
      float a = __expf(l - nm);
      d = d * sf + a;
#pragma unroll
      for (int j = 0; j < 8; j++) acc[j] = acc[j] * sf + a * u_[j];
      m = nm;
    }
    // merge the 4 groups' online-softmax states
#pragma unroll
    for (int off = 16; off < 64; off <<= 1) {
      float m2 = __shfl_xor(m, off);
      float d2 = __shfl_xor(d, off);
      float nm = fmaxf(m, m2);
      float s1 = __expf(m - nm), s2 = __expf(m2 - nm);
      d = d * s1 + d2 * s2;
#pragma unroll
      for (int j = 0; j < 8; j++) {
        float a2 = __shfl_xor(acc[j], off);
        acc[j] = acc[j] * s1 + a2 * s2;
      }
      m = nm;
    }
    float inv = 1.f / d;
    sk0.x += acc[0] * inv; sk0.y += acc[1] * inv;
    sk0.z += acc[2] * inv; sk0.w += acc[3] * inv;
    sk1.x += acc[4] * inv; sk1.y += acc[5] * inv;
    sk1.z += acc[6] * inv; sk1.w += acc[7] * inv;
  }
  sk0.x = (sk0.x > 0.f) ? sk0.x : 0.01f * sk0.x;
  sk0.y = (sk0.y > 0.f) ? sk0.y : 0.01f * sk0.y;
  sk0.z = (sk0.z > 0.f) ? sk0.z : 0.01f * sk0.z;
  sk0.w = (sk0.w > 0.f) ? sk0.w : 0.01f * sk0.w;
  sk1.x = (sk1.x > 0.f) ? sk1.x : 0.01f * sk1.x;
  sk1.y = (sk1.y > 0.f) ? sk1.y : 0.01f * sk1.y;
  sk1.z = (sk1.z > 0.f) ? sk1.z : 0.01f * sk1.z;
  sk1.w = (sk1.w > 0.f) ? sk1.w : 0.01f * sk1.w;
  if (g == 0) {
    *(float4*)&h[(size_t)n * 128 + c] = sk0;
    *(float4*)&h[(size_t)n * 128 + c + 4] = sk1;
  }
}

// ======================= pool (batch is sorted) ==========================
__global__ void pool_kernel(const float* __restrict__ h, const int* __restrict__ batch,
                            float* __restrict__ gout, int N) {
  int c = threadIdx.x;  // 128
  int n0 = blockIdx.x * 128;
  if (n0 >= N) return;
  int n1 = min(n0 + 128, N);
  float acc = 0.f;
  int cur = batch[n0];
  for (int n = n0; n < n1; n++) {
    int b = batch[n];
    if (b != cur) { atomicAdd(&gout[cur * 128 + c], acc); acc = 0.f; cur = b; }
    acc += h[(size_t)n * 128 + c];
  }
  atomicAdd(&gout[cur * 128 + c], acc);
}

// ===================== fused MLP head (one block / graph) ================
__global__ __launch_bounds__(256) void mlp_fused(
    const float* __restrict__ gp,
    const float* __restrict__ Wl0, const float* __restrict__ bl0,
    const float* __restrict__ Wl1, const float* __restrict__ bl1,
    const float* __restrict__ Wl2, const float* __restrict__ bl2,
    float* __restrict__ out) {
  int g = blockIdx.x;
  int tid = threadIdx.x;
  __shared__ float xin[CDIM];
  __shared__ float h1[L0DIM];
  __shared__ float h2[L1DIM];
  __shared__ float r0s[4], r1s[4];
  if (tid < CDIM) xin[tid] = gp[g * CDIM + tid];
  __syncthreads();
  for (int c = tid; c < L0DIM; c += 256) {
    float a0 = 0.f, a1 = 0.f, a2 = 0.f, a3 = 0.f;
#pragma unroll 4
    for (int kk = 0; kk < CDIM; kk += 4) {
      a0 = fmaf(xin[kk + 0], Wl0[(kk + 0) * L0DIM + c], a0);
      a1 = fmaf(xin[kk + 1], Wl0[(kk + 1) * L0DIM + c], a1);
      a2 = fmaf(xin[kk + 2], Wl0[(kk + 2) * L0DIM + c], a2);
      a3 = fmaf(xin[kk + 3], Wl0[(kk + 3) * L0DIM + c], a3);
    }
    h1[c] = fmaxf((a0 + a1) + (a2 + a3) + bl0[c], 0.f);
  }
  __syncthreads();
  {
    int c = tid;
    float a0 = 0.f, a1 = 0.f, a2 = 0.f, a3 = 0.f;
#pragma unroll 4
    for (int kk = 0; kk < L0DIM; kk += 4) {
      a0 = fmaf(h1[kk + 0], Wl1[(kk + 0) * L1DIM + c], a0);
      a1 = fmaf(h1[kk + 1], Wl1[(kk + 1) * L1DIM + c], a1);
      a2 = fmaf(h1[kk + 2], Wl1[(kk + 2) * L1DIM + c], a2);
      a3 = fmaf(h1[kk + 3], Wl1[(kk + 3) * L1DIM + c], a3);
    }
    h2[c] = fmaxf((a0 + a1) + (a2 + a3) + bl1[c], 0.f);
  }
  __syncthreads();
  float p0 = h2[tid] * Wl2[tid * 2 + 0];
  float p1 = h2[tid] * Wl2[tid * 2 + 1];
#pragma unroll
  for (int off = 32; off > 0; off >>= 1) {
    p0 += __shfl_down(p0, off);
    p1 += __shfl_down(p1, off);
  }
  int wv = tid >> 6, ln = tid & 63;
  if (ln == 0) { r0s[wv] = p0; r1s[wv] = p1; }
  __syncthreads();
  if (tid == 0) out[g * 2 + 0] = r0s[0] + r0s[1] + r0s[2] + r0s[3] + bl2[0];
  if (tid == 1) out[g * 2 + 1] = r1s[0] + r1s[1] + r1s[2] + r1s[3] + bl2[1];
}

// ============================== launch ==================================
extern "C" void kernel_launch(void* const* d_in, const int* in_sizes, int n_in,
                              void* d_out, int out_size, void* d_ws, size_t ws_size,
                              hipStream_t stream) {
  const int N = N_NODES, E = N_EDGES;
  const float* x    = (const float*)d_in[0];
  const int*   ei   = (const int*)d_in[1];
  const float* attr = (const float*)d_in[2];
  const int*   batch= (const int*)d_in[3];
  const int* src = ei;
  const int* dst = ei + E;

  const float *Wq0 = (const float*)d_in[4],  *bq0 = (const float*)d_in[5];
  const float *Wk0 = (const float*)d_in[6],  *bk0 = (const float*)d_in[7];
  const float *Wv0 = (const float*)d_in[8],  *bv0 = (const float*)d_in[9];
  const float *We0 = (const float*)d_in[10];
  const float *Ws0 = (const float*)d_in[11], *bs0 = (const float*)d_in[12];
  const float *Wq1 = (const float*)d_in[13], *bq1 = (const float*)d_in[14];
  const float *Wk1 = (const float*)d_in[15], *bk1 = (const float*)d_in[16];
  const float *Wv1 = (const float*)d_in[17], *bv1 = (const float*)d_in[18];
  const float *We1 = (const float*)d_in[19];
  const float *Ws1 = (const float*)d_in[20], *bs1 = (const float*)d_in[21];
  const float *Wl0 = (const float*)d_in[22], *bl0 = (const float*)d_in[23];
  const float *Wl1 = (const float*)d_in[24], *bl1 = (const float*)d_in[25];
  const float *Wl2 = (const float*)d_in[26], *bl2 = (const float*)d_in[27];

  size_t off = 0;
  auto carve = [&](size_t bytes) {
    void* p = (char*)d_ws + off;
    off += (bytes + 255) & ~(size_t)255;
    return p;
  };
  float*  hA       = (float*)carve((size_t)N * CDIM * 4);
  float*  hB       = (float*)carve((size_t)N * CDIM * 4);
  float*  qb       = (float*)carve((size_t)N * CDIM * 4);
  ushort* kvb      = (ushort*)carve((size_t)N * 256 * 2);
  int*    indptr   = (int*)carve((size_t)(N + 1) * 4);
  int*    csr_src  = (int*)carve((size_t)E * 4);
  float4* csr_attr = (float4*)carve((size_t)E * 16);
  int*    counts   = (int*)carve((size_t)N * 4);
  int*    cursor   = (int*)carve((size_t)N * 4);
  int*    excl     = (int*)carve((size_t)N * 4);
  int*    bsums    = (int*)carve((size_t)64 * 4);
  ushort* wt1      = (ushort*)carve((size_t)4 * 16384 * 2);
  float*  gp       = (float*)carve((size_t)GDIM * CDIM * 4);

  hipMemsetAsync(counts, 0, (size_t)N * 4, stream);
  hipMemsetAsync(cursor, 0, (size_t)N * 4, stream);
  hipMemsetAsync(gp, 0, (size_t)GDIM * CDIM * 4, stream);

  int nscan = (N + 1023) / 1024;
  hist_kernel<<<(E + 255) / 256, 256, 0, stream>>>(dst, counts, E);
  scan_blocks<<<nscan, 1024, 0, stream>>>(counts, excl, bsums, N);
  scan_sums<<<1, 64, 0, stream>>>(bsums, nscan);
  scan_add<<<nscan, 1024, 0, stream>>>(excl, bsums, indptr, N, E);
  scatter2_kernel<<<(E + 255) / 256, 256, 0, stream>>>(dst, src, attr, indptr, cursor,
                                                       csr_src, csr_attr, E);
  prep_w<<<256, 256, 0, stream>>>(Wq1, Wk1, Wv1, Ws1, wt1);

  int naBlocks = (N + 3) / 4;
  dim3 gemmGrid((N + 63) / 64, 1, 4);

  // ---- layer 0 (din=4) ----
  l0_qkvs<<<(N * 128 + 255) / 256, 256, 0, stream>>>(
      x, Wq0, bq0, Wk0, bk0, Wv0, bv0, Ws0, bs0, qb, kvb, hA, N);
  attn_fused<<<naBlocks, 256, 0, stream>>>(qb, kvb, indptr, csr_src, csr_attr, We0, hA, N);

  // ---- layer 1 (shared weights) ----
  gemm_mfma<<<gemmGrid, 256, 0, stream>>>(hA, wt1, bq1, bk1, bv1, bs1, qb, kvb, hB, N);
  attn_fused<<<naBlocks, 256, 0, stream>>>(qb, kvb, indptr, csr_src, csr_attr, We1, hB, N);

  // ---- layer 2 (same weights) ----
  gemm_mfma<<<gemmGrid, 256, 0, stream>>>(hB, wt1, bq1, bk1, bv1, bs1, qb, kvb, hA, N);
  attn_fused<<<naBlocks, 256, 0, stream>>>(qb, kvb, indptr, csr_src, csr_attr, We1, hA, N);

  // ---- pool + fused MLP ----
  pool_kernel<<<(N + 127) / 128, 128, 0, stream>>>(hA, batch, gp, N);
  mlp_fused<<<GDIM, 256, 0, stream>>>(gp, Wl0, bl0, Wl1, bl1, Wl2, bl2, (float*)d_out);
}

// Round 5
// 586.625 us; speedup vs baseline: 2.5905x; 1.0911x over previous
//
#include <hip/hip_runtime.h>
#include <math.h>

#define N_NODES 50000
#define N_EDGES 800000
#define CDIM    128
#define GDIM    128
#define L0DIM   512
#define L1DIM   256

typedef unsigned int uint;
typedef unsigned short ushort;
typedef __attribute__((ext_vector_type(8))) short short8;
typedef __attribute__((ext_vector_type(4))) float f32x4;

__device__ inline ushort f2bf(float f) {
  uint u = __float_as_uint(f);
  uint r = (u + 0x7fffu + ((u >> 16) & 1u)) >> 16;
  return (ushort)r;
}
__device__ inline float bflo(uint u) { return __uint_as_float(u << 16); }
__device__ inline float bfhi(uint u) { return __uint_as_float(u & 0xffff0000u); }

// ============================ CSR build =================================
__global__ void hist_kernel(const int* __restrict__ dst, int* counts, int E) {
  int e = blockIdx.x * 256 + threadIdx.x;
  if (e < E) atomicAdd(&counts[dst[e]], 1);
}

__global__ void scan_blocks(const int* __restrict__ counts, int* excl, int* bsums, int N) {
  __shared__ int s[1024];
  int tid = threadIdx.x;
  int i = blockIdx.x * 1024 + tid;
  int v = (i < N) ? counts[i] : 0;
  s[tid] = v;
  __syncthreads();
  for (int off = 1; off < 1024; off <<= 1) {
    int t = (tid >= off) ? s[tid - off] : 0;
    __syncthreads();
    s[tid] += t;
    __syncthreads();
  }
  if (i < N) excl[i] = s[tid] - v;
  if (tid == 1023) bsums[blockIdx.x] = s[1023];
}

// single-wave exclusive scan of block sums (nb <= 64)
__global__ void scan_sums(int* bsums, int nb) {
  int lane = threadIdx.x;  // 64
  int orig = (lane < nb) ? bsums[lane] : 0;
  int v = orig;
#pragma unroll
  for (int off = 1; off < 64; off <<= 1) {
    int t = __shfl_up(v, off);
    if (lane >= off) v += t;
  }
  if (lane < nb) bsums[lane] = v - orig;  // exclusive
}

__global__ void scan_add(const int* __restrict__ excl, const int* __restrict__ bsums,
                         int* indptr, int N, int E) {
  int i = blockIdx.x * 1024 + threadIdx.x;
  if (i < N) indptr[i] = excl[i] + bsums[blockIdx.x];
  if (i == 0) indptr[N] = E;
}

__global__ void scatter2_kernel(const int* __restrict__ dst, const int* __restrict__ src,
                                const float* __restrict__ attr,
                                const int* __restrict__ indptr,
                                int* cursor, int* csr_src, float4* csr_attr, int E) {
  int e = blockIdx.x * 256 + threadIdx.x;
  if (e < E) {
    int d = dst[e];
    int pos = atomicAdd(&cursor[d], 1);
    int i = indptr[d] + pos;
    csr_src[i] = src[e];
    csr_attr[i] = make_float4(attr[e * 3 + 0], attr[e * 3 + 1], attr[e * 3 + 2], 0.f);
  }
}

// ===================== layer 0 (din=4) q/kv/skip ========================
__global__ void l0_qkvs(const float* __restrict__ x,
                        const float* __restrict__ Wq, const float* __restrict__ bq,
                        const float* __restrict__ Wk, const float* __restrict__ bk,
                        const float* __restrict__ Wv, const float* __restrict__ bv,
                        const float* __restrict__ Ws, const float* __restrict__ bs,
                        float* __restrict__ q, ushort* __restrict__ kvb,
                        float* __restrict__ hs, int N) {
  __shared__ float W[4][4][128];
  __shared__ float B[4][128];
  int tid = threadIdx.x;
  for (int i = tid; i < 4 * 128; i += 256) {
    W[0][i >> 7][i & 127] = Wq[i];
    W[1][i >> 7][i & 127] = Wk[i];
    W[2][i >> 7][i & 127] = Wv[i];
    W[3][i >> 7][i & 127] = Ws[i];
  }
  for (int i = tid; i < 128; i += 256) {
    B[0][i] = bq[i]; B[1][i] = bk[i]; B[2][i] = bv[i]; B[3][i] = bs[i];
  }
  __syncthreads();
  int gid = blockIdx.x * 256 + tid;
  int n = gid >> 7, c = gid & 127;
  if (n >= N) return;
  float x0 = x[n * 4 + 0], x1 = x[n * 4 + 1], x2 = x[n * 4 + 2], x3 = x[n * 4 + 3];
  float qv = x0 * W[0][0][c] + x1 * W[0][1][c] + x2 * W[0][2][c] + x3 * W[0][3][c] + B[0][c];
  float kv = x0 * W[1][0][c] + x1 * W[1][1][c] + x2 * W[1][2][c] + x3 * W[1][3][c] + B[1][c];
  float vv = x0 * W[2][0][c] + x1 * W[2][1][c] + x2 * W[2][2][c] + x3 * W[2][3][c] + B[2][c];
  float sv = x0 * W[3][0][c] + x1 * W[3][1][c] + x2 * W[3][2][c] + x3 * W[3][3][c] + B[3][c];
  q[n * 128 + c] = qv;
  kvb[(size_t)n * 256 + c]       = f2bf(kv);
  kvb[(size_t)n * 256 + 128 + c] = f2bf(vv);
  hs[n * 128 + c] = sv;
}

// ============== W -> bf16 transposed: wt[z][c][k] = W_z[k][c] =============
__global__ void prep_w(const float* __restrict__ Wq, const float* __restrict__ Wk,
                       const float* __restrict__ Wv, const float* __restrict__ Ws,
                       ushort* __restrict__ wt) {
  int idx = blockIdx.x * 256 + threadIdx.x;  // 4*16384
  int z = idx >> 14, rem = idx & 16383;
  int k_ = rem >> 7, c_ = rem & 127;
  const float* W = (z == 0) ? Wq : (z == 1) ? Wk : (z == 2) ? Wv : Ws;
  wt[z * 16384 + c_ * 128 + k_] = f2bf(W[k_ * 128 + c_]);
}

// ============ layers 1-2 GEMM via MFMA: [N,128] @ [128,128] ==============
#define LDA 136
__global__ __launch_bounds__(256) void gemm_mfma(
    const float* __restrict__ H, const ushort* __restrict__ wtg,
    const float* __restrict__ bq, const float* __restrict__ bk,
    const float* __restrict__ bv, const float* __restrict__ bs,
    float* __restrict__ q, ushort* __restrict__ kvb,
    float* __restrict__ hs, int N) {
  int z = blockIdx.z;
  const float* bb = (z == 0) ? bq : (z == 1) ? bk : (z == 2) ? bv : bs;
  __shared__ ushort Alds[64 * LDA];
  __shared__ ushort Wlds[128 * LDA];
  int tid = threadIdx.x;
  int n0 = blockIdx.x * 64;

  {
    const uint* wg = (const uint*)(wtg + z * 16384);
    uint* wl = (uint*)Wlds;
    for (int i = tid; i < 8192; i += 256) {
      int c_ = i >> 6, kp = i & 63;
      wl[c_ * (LDA / 2) + kp] = wg[c_ * 64 + kp];
    }
  }
  {
    uint* al = (uint*)Alds;
    for (int i = tid; i < 4096; i += 256) {
      int r = i >> 6, kp = i & 63;
      int grow = n0 + r; grow = (grow < N) ? grow : (N - 1);
      float2 hv = *(const float2*)&H[(size_t)grow * 128 + 2 * kp];
      al[r * (LDA / 2) + kp] = (uint)f2bf(hv.x) | ((uint)f2bf(hv.y) << 16);
    }
  }
  __syncthreads();

  int w = tid >> 6, lane = tid & 63;
  int m_ = lane & 15, quad = lane >> 4;
  f32x4 acc[8];
#pragma unroll
  for (int ct = 0; ct < 8; ct++) acc[ct] = 0.f;

#pragma unroll
  for (int kc = 0; kc < 4; kc++) {
    short8 af = *(const short8*)&Alds[(w * 16 + m_) * LDA + kc * 32 + quad * 8];
#pragma unroll
    for (int ct = 0; ct < 8; ct++) {
      short8 bf = *(const short8*)&Wlds[(ct * 16 + m_) * LDA + kc * 32 + quad * 8];
      acc[ct] = __builtin_amdgcn_mfma_f32_16x16x32_bf16(af, bf, acc[ct], 0, 0, 0);
    }
  }

#pragma unroll
  for (int ct = 0; ct < 8; ct++) {
    int col = ct * 16 + m_;
    float bcol = bb[col];
#pragma unroll
    for (int reg = 0; reg < 4; reg++) {
      int n = n0 + w * 16 + quad * 4 + reg;
      if (n < N) {
        float o = acc[ct][reg] + bcol;
        if (z == 0)      q[(size_t)n * 128 + col] = o;
        else if (z == 3) hs[(size_t)n * 128 + col] = o;
        else             kvb[(size_t)n * 256 + ((z == 2) ? 128 : 0) + col] = f2bf(o);
      }
    }
  }
}

// ====== fused attention v3: ee eliminated algebraically =================
// logit = (q.k + at.t)/sqrt(C) with t = We^T q (per node);
// out = (sum a*v + (sum a*at)@We)/d + skip.
__global__ __launch_bounds__(256) void attn_fused(
    const float* __restrict__ q, const ushort* __restrict__ kv,
    const int* __restrict__ indptr, const int* __restrict__ csr_src,
    const float4* __restrict__ csr_attr, const float* __restrict__ We,
    float* __restrict__ h, int N) {
  __shared__ float WeS[384];
  int tid = threadIdx.x;
  for (int i = tid; i < 384; i += 256) WeS[i] = We[i];
  __syncthreads();
  int lane = tid & 63;
  int n = blockIdx.x * 4 + (tid >> 6);
  if (n >= N) return;
  int g = lane >> 4, gl = lane & 15;
  int c = gl * 8;  // 8 channels per lane
  float4 qa  = *(const float4*)&q[(size_t)n * 128 + c];
  float4 qb4 = *(const float4*)&q[(size_t)n * 128 + c + 4];
  float qv[8] = {qa.x, qa.y, qa.z, qa.w, qb4.x, qb4.y, qb4.z, qb4.w};
  float we0[8], we1[8], we2[8];
#pragma unroll
  for (int j = 0; j < 8; j++) {
    we0[j] = WeS[c + j]; we1[j] = WeS[128 + c + j]; we2[j] = WeS[256 + c + j];
  }
  // t = We^T q  (identical in all 4 groups)
  float t0 = 0.f, t1 = 0.f, t2 = 0.f;
#pragma unroll
  for (int j = 0; j < 8; j++) {
    t0 = fmaf(we0[j], qv[j], t0);
    t1 = fmaf(we1[j], qv[j], t1);
    t2 = fmaf(we2[j], qv[j], t2);
  }
#pragma unroll
  for (int off = 1; off < 16; off <<= 1) {
    t0 += __shfl_xor(t0, off);
    t1 += __shfl_xor(t1, off);
    t2 += __shfl_xor(t2, off);
  }

  float4 sk0 = *(const float4*)&h[(size_t)n * 128 + c];
  float4 sk1 = *(const float4*)&h[(size_t)n * 128 + c + 4];
  int beg = indptr[n], end = indptr[n + 1];

  if (end > beg) {
    float m = -3.4e38f, d = 0.f;
    float sa0 = 0.f, sa1 = 0.f, sa2 = 0.f;
    float acc[8];
#pragma unroll
    for (int j = 0; j < 8; j++) acc[j] = 0.f;
    const uint* kvw = (const uint*)kv;
    int i = beg + g;
    int sj = 0; float4 at = make_float4(0.f, 0.f, 0.f, 0.f);
    if (i < end) { sj = csr_src[i]; at = csr_attr[i]; }
    for (; i < end; i += 4) {
      int sjc = sj; float4 atc = at;
      int inx = i + 4;
      if (inx < end) { sj = csr_src[inx]; at = csr_attr[inx]; }
      const uint4* kp = (const uint4*)(kvw + (size_t)sjc * 128);
      uint4 kr = kp[gl];
      uint4 vr = kp[16 + gl];
      float kx[8], vx[8];
      kx[0] = bflo(kr.x); kx[1] = bfhi(kr.x); kx[2] = bflo(kr.y); kx[3] = bfhi(kr.y);
      kx[4] = bflo(kr.z); kx[5] = bfhi(kr.z); kx[6] = bflo(kr.w); kx[7] = bfhi(kr.w);
      vx[0] = bflo(vr.x); vx[1] = bfhi(vr.x); vx[2] = bflo(vr.y); vx[3] = bfhi(vr.y);
      vx[4] = bflo(vr.z); vx[5] = bfhi(vr.z); vx[6] = bflo(vr.w); vx[7] = bfhi(vr.w);
      float p = 0.f;
#pragma unroll
      for (int j = 0; j < 8; j++) p = fmaf(qv[j], kx[j], p);
      p += __shfl_xor(p, 1); p += __shfl_xor(p, 2);
      p += __shfl_xor(p, 4); p += __shfl_xor(p, 8);
      p = fmaf(atc.x, t0, p);
      p = fmaf(atc.y, t1, p);
      p = fmaf(atc.z, t2, p);
      float l = p * 0.08838834764831845f;  // 1/sqrt(128)
      float nm = fmaxf(m, l);
      float sf = __expf(m - nm);
      float a = __expf(l - nm);
      d = d * sf + a;
      sa0 = sa0 * sf + a * atc.x;
      sa1 = sa1 * sf + a * atc.y;
      sa2 = sa2 * sf + a * atc.z;
#pragma unroll
      for (int j = 0; j < 8; j++) acc[j] = fmaf(acc[j], sf, a * vx[j]);
      m = nm;
    }
    // merge the 4 groups' online-softmax states
#pragma unroll
    for (int off = 16; off < 64; off <<= 1) {
      float m2 = __shfl_xor(m, off);
      float d2 = __shfl_xor(d, off);
      float nm = fmaxf(m, m2);
      float s1 = __expf(m - nm), s2 = __expf(m2 - nm);
      d = d * s1 + d2 * s2;
      sa0 = sa0 * s1 + __shfl_xor(sa0, off) * s2;
      sa1 = sa1 * s1 + __shfl_xor(sa1, off) * s2;
      sa2 = sa2 * s1 + __shfl_xor(sa2, off) * s2;
#pragma unroll
      for (int j = 0; j < 8; j++) {
        float a2 = __shfl_xor(acc[j], off);
        acc[j] = acc[j] * s1 + a2 * s2;
      }
      m = nm;
    }
    float inv = 1.f / d;
    float o[8];
#pragma unroll
    for (int j = 0; j < 8; j++) {
      float ecorr = sa0 * we0[j] + sa1 * we1[j] + sa2 * we2[j];
      o[j] = (acc[j] + ecorr) * inv;
    }
    sk0.x += o[0]; sk0.y += o[1]; sk0.z += o[2]; sk0.w += o[3];
    sk1.x += o[4]; sk1.y += o[5]; sk1.z += o[6]; sk1.w += o[7];
  }
  sk0.x = (sk0.x > 0.f) ? sk0.x : 0.01f * sk0.x;
  sk0.y = (sk0.y > 0.f) ? sk0.y : 0.01f * sk0.y;
  sk0.z = (sk0.z > 0.f) ? sk0.z : 0.01f * sk0.z;
  sk0.w = (sk0.w > 0.f) ? sk0.w : 0.01f * sk0.w;
  sk1.x = (sk1.x > 0.f) ? sk1.x : 0.01f * sk1.x;
  sk1.y = (sk1.y > 0.f) ? sk1.y : 0.01f * sk1.y;
  sk1.z = (sk1.z > 0.f) ? sk1.z : 0.01f * sk1.z;
  sk1.w = (sk1.w > 0.f) ? sk1.w : 0.01f * sk1.w;
  if (g == 0) {
    *(float4*)&h[(size_t)n * 128 + c] = sk0;
    *(float4*)&h[(size_t)n * 128 + c + 4] = sk1;
  }
}

// ======================= pool (batch is sorted) ==========================
// 782 blocks x 256 threads; 4 node-substreams of 16, float2 channels
__global__ void pool_kernel(const float* __restrict__ h, const int* __restrict__ batch,
                            float* __restrict__ gout, int N) {
  int tid = threadIdx.x;
  int sub = tid >> 6;
  int c = 2 * (tid & 63);
  int n0 = blockIdx.x * 64 + sub * 16;
  if (n0 >= N) return;
  int n1 = min(n0 + 16, N);
  float a0 = 0.f, a1 = 0.f;
  int cur = batch[n0];
  for (int n = n0; n < n1; n++) {
    int b = batch[n];
    if (b != cur) {
      atomicAdd(&gout[cur * 128 + c], a0);
      atomicAdd(&gout[cur * 128 + c + 1], a1);
      a0 = 0.f; a1 = 0.f; cur = b;
    }
    float2 hv = *(const float2*)&h[(size_t)n * 128 + c];
    a0 += hv.x; a1 += hv.y;
  }
  atomicAdd(&gout[cur * 128 + c], a0);
  atomicAdd(&gout[cur * 128 + c + 1], a1);
}

// ===================== fused MLP head (one block / graph) ================
__global__ __launch_bounds__(256) void mlp_fused(
    const float* __restrict__ gp,
    const float* __restrict__ Wl0, const float* __restrict__ bl0,
    const float* __restrict__ Wl1, const float* __restrict__ bl1,
    const float* __restrict__ Wl2, const float* __restrict__ bl2,
    float* __restrict__ out) {
  int g = blockIdx.x;
  int tid = threadIdx.x;
  __shared__ float xin[CDIM];
  __shared__ float h1[L0DIM];
  __shared__ float h2[L1DIM];
  __shared__ float r0s[4], r1s[4];
  if (tid < CDIM) xin[tid] = gp[g * CDIM + tid];
  __syncthreads();
  for (int c = tid; c < L0DIM; c += 256) {
    float a0 = 0.f, a1 = 0.f, a2 = 0.f, a3 = 0.f;
#pragma unroll 4
    for (int kk = 0; kk < CDIM; kk += 4) {
      a0 = fmaf(xin[kk + 0], Wl0[(kk + 0) * L0DIM + c], a0);
      a1 = fmaf(xin[kk + 1], Wl0[(kk + 1) * L0DIM + c], a1);
      a2 = fmaf(xin[kk + 2], Wl0[(kk + 2) * L0DIM + c], a2);
      a3 = fmaf(xin[kk + 3], Wl0[(kk + 3) * L0DIM + c], a3);
    }
    h1[c] = fmaxf((a0 + a1) + (a2 + a3) + bl0[c], 0.f);
  }
  __syncthreads();
  {
    int c = tid;
    float a0 = 0.f, a1 = 0.f, a2 = 0.f, a3 = 0.f;
#pragma unroll 4
    for (int kk = 0; kk < L0DIM; kk += 4) {
      a0 = fmaf(h1[kk + 0], Wl1[(kk + 0) * L1DIM + c], a0);
      a1 = fmaf(h1[kk + 1], Wl1[(kk + 1) * L1DIM + c], a1);
      a2 = fmaf(h1[kk + 2], Wl1[(kk + 2) * L1DIM + c], a2);
      a3 = fmaf(h1[kk + 3], Wl1[(kk + 3) * L1DIM + c], a3);
    }
    h2[c] = fmaxf((a0 + a1) + (a2 + a3) + bl1[c], 0.f);
  }
  __syncthreads();
  float p0 = h2[tid] * Wl2[tid * 2 + 0];
  float p1 = h2[tid] * Wl2[tid * 2 + 1];
#pragma unroll
  for (int off = 32; off > 0; off >>= 1) {
    p0 += __shfl_down(p0, off);
    p1 += __shfl_down(p1, off);
  }
  int wv = tid >> 6, ln = tid & 63;
  if (ln == 0) { r0s[wv] = p0; r1s[wv] = p1; }
  __syncthreads();
  if (tid == 0) out[g * 2 + 0] = r0s[0] + r0s[1] + r0s[2] + r0s[3] + bl2[0];
  if (tid == 1) out[g * 2 + 1] = r1s[0] + r1s[1] + r1s[2] + r1s[3] + bl2[1];
}

// ============================== launch ==================================
extern "C" void kernel_launch(void* const* d_in, const int* in_sizes, int n_in,
                              void* d_out, int out_size, void* d_ws, size_t ws_size,
                              hipStream_t stream) {
  const int N = N_NODES, E = N_EDGES;
  const float* x    = (const float*)d_in[0];
  const int*   ei   = (const int*)d_in[1];
  const float* attr = (const float*)d_in[2];
  const int*   batch= (const int*)d_in[3];
  const int* src = ei;
  const int* dst = ei + E;

  const float *Wq0 = (const float*)d_in[4],  *bq0 = (const float*)d_in[5];
  const float *Wk0 = (const float*)d_in[6],  *bk0 = (const float*)d_in[7];
  const float *Wv0 = (const float*)d_in[8],  *bv0 = (const float*)d_in[9];
  const float *We0 = (const float*)d_in[10];
  const float *Ws0 = (const float*)d_in[11], *bs0 = (const float*)d_in[12];
  const float *Wq1 = (const float*)d_in[13], *bq1 = (const float*)d_in[14];
  const float *Wk1 = (const float*)d_in[15], *bk1 = (const float*)d_in[16];
  const float *Wv1 = (const float*)d_in[17], *bv1 = (const float*)d_in[18];
  const float *We1 = (const float*)d_in[19];
  const float *Ws1 = (const float*)d_in[20], *bs1 = (const float*)d_in[21];
  const float *Wl0 = (const float*)d_in[22], *bl0 = (const float*)d_in[23];
  const float *Wl1 = (const float*)d_in[24], *bl1 = (const float*)d_in[25];
  const float *Wl2 = (const float*)d_in[26], *bl2 = (const float*)d_in[27];

  size_t off = 0;
  auto carve = [&](size_t bytes) {
    void* p = (char*)d_ws + off;
    off += (bytes + 255) & ~(size_t)255;
    return p;
  };
  float*  hA       = (float*)carve((size_t)N * CDIM * 4);
  float*  hB       = (float*)carve((size_t)N * CDIM * 4);
  float*  qb       = (float*)carve((size_t)N * CDIM * 4);
  ushort* kvb      = (ushort*)carve((size_t)N * 256 * 2);
  int*    indptr   = (int*)carve((size_t)(N + 1) * 4);
  int*    csr_src  = (int*)carve((size_t)E * 4);
  float4* csr_attr = (float4*)carve((size_t)E * 16);
  int*    cc       = (int*)carve((size_t)2 * N * 4);   // counts | cursor
  int*    counts   = cc;
  int*    cursor   = cc + N;
  int*    excl     = (int*)carve((size_t)N * 4);
  int*    bsums    = (int*)carve((size_t)64 * 4);
  ushort* wt1      = (ushort*)carve((size_t)4 * 16384 * 2);
  float*  gp       = (float*)carve((size_t)GDIM * CDIM * 4);

  hipMemsetAsync(cc, 0, (size_t)2 * N * 4, stream);
  hipMemsetAsync(gp, 0, (size_t)GDIM * CDIM * 4, stream);

  int nscan = (N + 1023) / 1024;
  hist_kernel<<<(E + 255) / 256, 256, 0, stream>>>(dst, counts, E);
  scan_blocks<<<nscan, 1024, 0, stream>>>(counts, excl, bsums, N);
  scan_sums<<<1, 64, 0, stream>>>(bsums, nscan);
  scan_add<<<nscan, 1024, 0, stream>>>(excl, bsums, indptr, N, E);
  scatter2_kernel<<<(E + 255) / 256, 256, 0, stream>>>(dst, src, attr, indptr, cursor,
                                                       csr_src, csr_attr, E);
  prep_w<<<256, 256, 0, stream>>>(Wq1, Wk1, Wv1, Ws1, wt1);

  int naBlocks = (N + 3) / 4;
  dim3 gemmGrid((N + 63) / 64, 1, 4);

  // ---- layer 0 (din=4) ----
  l0_qkvs<<<(N * 128 + 255) / 256, 256, 0, stream>>>(
      x, Wq0, bq0, Wk0, bk0, Wv0, bv0, Ws0, bs0, qb, kvb, hA, N);
  attn_fused<<<naBlocks, 256, 0, stream>>>(qb, kvb, indptr, csr_src, csr_attr, We0, hA, N);

  // ---- layer 1 (shared weights) ----
  gemm_mfma<<<gemmGrid, 256, 0, stream>>>(hA, wt1, bq1, bk1, bv1, bs1, qb, kvb, hB, N);
  attn_fused<<<naBlocks, 256, 0, stream>>>(qb, kvb, indptr, csr_src, csr_attr, We1, hB, N);

  // ---- layer 2 (same weights) ----
  gemm_mfma<<<gemmGrid, 256, 0, stream>>>(hB, wt1, bq1, bk1, bv1, bs1, qb, kvb, hA, N);
  attn_fused<<<naBlocks, 256, 0, stream>>>(qb, kvb, indptr, csr_src, csr_attr, We1, hA, N);

  // ---- pool + fused MLP ----
  pool_kernel<<<(N + 63) / 64, 256, 0, stream>>>(hA, batch, gp, N);
  mlp_fused<<<GDIM, 256, 0, stream>>>(gp, Wl0, bl0, Wl1, bl1, Wl2, bl2, (float*)d_out);
}